// Round 4
// baseline (2830.258 us; speedup 1.0000x reference)
//
#include <hip/hip_runtime.h>
#include <math.h>

#define NN 100000
#define NE 1000000
#define DH 64
constexpr int ETOT = NE + NN;

// ---- float <-> monotone-uint encoding for atomic max on floats ----
__device__ inline unsigned f2key(float f) {
    unsigned b = __float_as_uint(f);
    return (b & 0x80000000u) ? ~b : (b | 0x80000000u);
}
__device__ inline float key2f(unsigned k) {
    unsigned b = (k & 0x80000000u) ? (k & 0x7fffffffu) : ~k;
    return __uint_as_float(b);
}

// ---------------- self-loop attr ----------------

__global__ void k_zero_init(int* __restrict__ deg, float* __restrict__ loop_sum) {
    int i = blockIdx.x * blockDim.x + threadIdx.x;
    if (i < NN) {
        deg[i] = 0;
        loop_sum[2 * i] = 0.f;
        loop_sum[2 * i + 1] = 0.f;
    }
}

__global__ void k_deg_loopsum(const int* __restrict__ ei, const float* __restrict__ ea,
                              int* __restrict__ deg, float* __restrict__ loop_sum) {
    int e = blockIdx.x * blockDim.x + threadIdx.x;
    if (e < NE) {
        int d = ei[NE + e];
        atomicAdd(&deg[d], 1);
        atomicAdd(&loop_sum[2 * d], ea[2 * e]);
        atomicAdd(&loop_sum[2 * d + 1], ea[2 * e + 1]);
    }
}

__global__ void k_loop_attr(const int* __restrict__ deg, const float* __restrict__ loop_sum,
                            float* __restrict__ loop_attr) {
    int n = blockIdx.x * blockDim.x + threadIdx.x;
    if (n < NN) {
        float dv = fmaxf((float)deg[n], 1.0f);
        loop_attr[2 * n] = loop_sum[2 * n] / dv;
        loop_attr[2 * n + 1] = loop_sum[2 * n + 1] / dv;
    }
}

// ---------------- encoder: h = relu(x @ enc_W + enc_b) ----------------

__global__ void k_encoder(const float* __restrict__ x, const float* __restrict__ W,
                          const float* __restrict__ b, float* __restrict__ h) {
    int idx = blockIdx.x * blockDim.x + threadIdx.x;
    int n = idx >> 6, d = idx & 63;
    if (n < NN) {
        float v = x[2 * n] * W[d] + x[2 * n + 1] * W[DH + d] + b[d];
        h[idx] = fmaxf(v, 0.f);
    }
}

// ---------------- xw = h @ lin_W, scalar: one thread per (n,c) ----------------

template <int C>
__global__ void k_xw_s(const float* __restrict__ h, const float* __restrict__ W,
                       float* __restrict__ xw) {
    int gid = blockIdx.x * blockDim.x + threadIdx.x;
    int n = gid / C, c = gid % C;
    if (n >= NN) return;
    float s = 0.f;
    for (int k = 0; k < DH; k++) s += h[n * DH + k] * W[k * C + c];
    xw[gid] = s;
}

// ---------------- a_src/a_dst: one thread per (n,h) ----------------

template <int H>
__global__ void k_att_s(const float* __restrict__ xw, const float* __restrict__ att_src,
                        const float* __restrict__ att_dst,
                        float* __restrict__ a_src, float* __restrict__ a_dst) {
    int idx = blockIdx.x * blockDim.x + threadIdx.x;
    int n = idx / H, hh = idx % H;
    if (n >= NN) return;
    float ps = 0.f, pd = 0.f;
    for (int d = 0; d < DH; d++) {
        float xv = xw[(size_t)n * (H * DH) + hh * DH + d];
        ps += xv * att_src[hh * DH + d];
        pd += xv * att_dst[hh * DH + d];
    }
    a_src[idx] = ps;
    a_dst[idx] = pd;
}

// ---------------- edge coef: coef[w][h] = sum_d edge_W[w][h*D+d]*att_edge[h][d] ----------------

template <int H>
__global__ void k_coef_s(const float* __restrict__ edge_W, const float* __restrict__ att_edge,
                         float* __restrict__ coef) {
    if (blockIdx.x || threadIdx.x) return;
    for (int w = 0; w < 2; w++)
        for (int h = 0; h < H; h++) {
            float s = 0.f;
            for (int d = 0; d < DH; d++)
                s += edge_W[w * H * DH + h * DH + d] * att_edge[h * DH + d];
            coef[w * H + h] = s;
        }
}

// ---------------- segment softmax over dst, 3 edge passes, logits recomputed ----------------

template <int H>
__global__ void k_init_mden(unsigned* __restrict__ mkey, float* __restrict__ den) {
    int i = blockIdx.x * blockDim.x + threadIdx.x;
    if (i < NN * H) {
        mkey[i] = f2key(-1e30f);
        den[i] = 0.f;
    }
}

__global__ void k_zero_h(float* __restrict__ p) {
    int i = blockIdx.x * blockDim.x + threadIdx.x;
    if (i < NN * DH) p[i] = 0.f;
}

template <int H>
__device__ inline void edge_fields(int e, const int* ei, const float* ea, const float* loop_attr,
                                   int& s, int& d, float& e0, float& e1) {
    if (e < NE) {
        s = ei[e]; d = ei[NE + e];
        e0 = ea[2 * e]; e1 = ea[2 * e + 1];
    } else {
        s = d = e - NE;
        e0 = loop_attr[2 * s]; e1 = loop_attr[2 * s + 1];
    }
}

template <int H>
__device__ inline float logit_of(int s, int d, float e0, float e1, int h,
                                 const float* a_src, const float* a_dst, const float* coef) {
    float lg = a_src[s * H + h] + a_dst[d * H + h] + e0 * coef[h] + e1 * coef[H + h];
    return (lg > 0.f) ? lg : 0.2f * lg;
}

template <int H>
__global__ void k_pass1(const int* __restrict__ ei, const float* __restrict__ ea,
                        const float* __restrict__ loop_attr,
                        const float* __restrict__ a_src, const float* __restrict__ a_dst,
                        const float* __restrict__ coef, unsigned* __restrict__ mkey) {
    int e = blockIdx.x * blockDim.x + threadIdx.x;
    if (e >= ETOT) return;
    int s, d; float e0, e1;
    edge_fields<H>(e, ei, ea, loop_attr, s, d, e0, e1);
    for (int h = 0; h < H; h++) {
        float lg = logit_of<H>(s, d, e0, e1, h, a_src, a_dst, coef);
        atomicMax(&mkey[d * H + h], f2key(lg));
    }
}

template <int H>
__global__ void k_pass2(const int* __restrict__ ei, const float* __restrict__ ea,
                        const float* __restrict__ loop_attr,
                        const float* __restrict__ a_src, const float* __restrict__ a_dst,
                        const float* __restrict__ coef, const unsigned* __restrict__ mkey,
                        float* __restrict__ den) {
    int e = blockIdx.x * blockDim.x + threadIdx.x;
    if (e >= ETOT) return;
    int s, d; float e0, e1;
    edge_fields<H>(e, ei, ea, loop_attr, s, d, e0, e1);
    for (int h = 0; h < H; h++) {
        float lg = logit_of<H>(s, d, e0, e1, h, a_src, a_dst, coef);
        float ex = __expf(lg - key2f(mkey[d * H + h]));
        atomicAdd(&den[d * H + h], ex);
    }
}

// one thread per (edge, dim): recompute alpha, gather xw, scatter-add head-mean
template <int H>
__global__ void k_pass3(const int* __restrict__ ei, const float* __restrict__ ea,
                        const float* __restrict__ loop_attr,
                        const float* __restrict__ a_src, const float* __restrict__ a_dst,
                        const float* __restrict__ coef, const unsigned* __restrict__ mkey,
                        const float* __restrict__ den, const float* __restrict__ xw,
                        float* __restrict__ acc) {
    long long gid = (long long)blockIdx.x * blockDim.x + threadIdx.x;
    int e = (int)(gid >> 6);
    int dim = (int)(gid & 63);
    if (e >= ETOT) return;
    int s, d; float e0, e1;
    edge_fields<H>(e, ei, ea, loop_attr, s, d, e0, e1);
    float v = 0.f;
    for (int h = 0; h < H; h++) {
        float lg = logit_of<H>(s, d, e0, e1, h, a_src, a_dst, coef);
        float ex = __expf(lg - key2f(mkey[d * H + h]));
        float alpha = ex / (den[d * H + h] + 1e-16f);
        v += alpha * xw[(size_t)s * (H * DH) + h * DH + dim];
    }
    atomicAdd(&acc[d * DH + dim], v * (1.0f / H));
}

__global__ void k_epilogue(float* __restrict__ hout, const float* __restrict__ hin,
                           const float* __restrict__ bias) {
    int idx = blockIdx.x * blockDim.x + threadIdx.x;
    if (idx < NN * DH) {
        float v = hout[idx] + bias[idx & 63];
        hout[idx] = fmaxf(v, 0.f) + hin[idx];
    }
}

// ---------------- final MLP head, scalar: one thread per node ----------------

__global__ void k_head_s(const float* __restrict__ h, const float* __restrict__ fc1_W,
                         const float* __restrict__ fc1_b, const float* __restrict__ fc2_W,
                         const float* __restrict__ fc2_b, float* __restrict__ out) {
    int n = blockIdx.x * blockDim.x + threadIdx.x;
    if (n >= NN) return;
    float y[32];
#pragma unroll
    for (int c = 0; c < 32; c++) y[c] = fc1_b[c];
    for (int k = 0; k < DH; k++) {
        float hk = h[n * DH + k];
#pragma unroll
        for (int c = 0; c < 32; c++) y[c] += hk * fc1_W[k * 32 + c];
    }
    float o0 = fc2_b[0], o1 = fc2_b[1];
#pragma unroll
    for (int c = 0; c < 32; c++) {
        float yr = fmaxf(y[c], 0.f);
        o0 += yr * fc2_W[c * 2];
        o1 += yr * fc2_W[c * 2 + 1];
    }
    out[2 * n] = tanhf(o0);
    out[2 * n + 1] = tanhf(o1);
}

// ---------------- launch ----------------

extern "C" void kernel_launch(void* const* d_in, const int* in_sizes, int n_in,
                              void* d_out, int out_size, void* d_ws, size_t ws_size,
                              hipStream_t stream) {
    const float* x     = (const float*)d_in[0];
    const int*   ei    = (const int*)d_in[1];
    const float* ea    = (const float*)d_in[2];
    const float* enc_W = (const float*)d_in[3];
    const float* enc_b = (const float*)d_in[4];
    const float* lin_W[3]    = {(const float*)d_in[5],  (const float*)d_in[11], (const float*)d_in[17]};
    const float* att_src[3]  = {(const float*)d_in[6],  (const float*)d_in[12], (const float*)d_in[18]};
    const float* att_dst[3]  = {(const float*)d_in[7],  (const float*)d_in[13], (const float*)d_in[19]};
    const float* edge_W[3]   = {(const float*)d_in[8],  (const float*)d_in[14], (const float*)d_in[20]};
    const float* att_edge[3] = {(const float*)d_in[9],  (const float*)d_in[15], (const float*)d_in[21]};
    const float* bias[3]     = {(const float*)d_in[10], (const float*)d_in[16], (const float*)d_in[22]};
    const float* fc1_W = (const float*)d_in[23];
    const float* fc1_b = (const float*)d_in[24];
    const float* fc2_W = (const float*)d_in[25];
    const float* fc2_b = (const float*)d_in[26];
    float* out = (float*)d_out;

    char* p = (char*)d_ws;
    auto alloc = [&](size_t bytes) -> void* {
        void* r = (void*)p;
        p += (bytes + 255) & ~(size_t)255;
        return r;
    };
    int*      deg       = (int*)alloc((size_t)NN * 4);
    float*    loop_sum  = (float*)alloc((size_t)NN * 8);
    float*    loop_attr = (float*)alloc((size_t)NN * 8);
    float*    a_srcB    = (float*)alloc((size_t)NN * 4 * 4);
    float*    a_dstB    = (float*)alloc((size_t)NN * 4 * 4);
    float*    coef      = (float*)alloc(256);
    unsigned* mkey      = (unsigned*)alloc((size_t)NN * 4 * 4);
    float*    den       = (float*)alloc((size_t)NN * 4 * 4);
    float*    xw        = (float*)alloc((size_t)NN * 256 * 4);
    float*    hA        = (float*)alloc((size_t)NN * DH * 4);
    float*    hB        = (float*)alloc((size_t)NN * DH * 4);

    const int BT = 256;
    const int nodeBlocks = (NN + BT - 1) / BT;
    const int edgeBlocks = (NE + BT - 1) / BT;
    const int etotBlocks = (ETOT + BT - 1) / BT;
    const int ndBlocks   = (NN * DH + BT - 1) / BT;
    const int edgeWaveBlocks = (int)(((long long)ETOT * 64 + BT - 1) / BT);

    k_zero_init<<<nodeBlocks, BT, 0, stream>>>(deg, loop_sum);
    k_deg_loopsum<<<edgeBlocks, BT, 0, stream>>>(ei, ea, deg, loop_sum);
    k_loop_attr<<<nodeBlocks, BT, 0, stream>>>(deg, loop_sum, loop_attr);
    k_encoder<<<ndBlocks, BT, 0, stream>>>(x, enc_W, enc_b, hA);

    float* hin = hA;
    float* hout = hB;

    for (int L = 0; L < 3; L++) {
        if (L < 2) {
            constexpr int H = 4;
            k_xw_s<H * DH><<<(NN * H * DH + BT - 1) / BT, BT, 0, stream>>>(hin, lin_W[L], xw);
            k_att_s<H><<<(NN * H + BT - 1) / BT, BT, 0, stream>>>(xw, att_src[L], att_dst[L], a_srcB, a_dstB);
            k_coef_s<H><<<1, 64, 0, stream>>>(edge_W[L], att_edge[L], coef);
            k_init_mden<H><<<(NN * H + BT - 1) / BT, BT, 0, stream>>>(mkey, den);
            k_zero_h<<<ndBlocks, BT, 0, stream>>>(hout);
            k_pass1<H><<<etotBlocks, BT, 0, stream>>>(ei, ea, loop_attr, a_srcB, a_dstB, coef, mkey);
            k_pass2<H><<<etotBlocks, BT, 0, stream>>>(ei, ea, loop_attr, a_srcB, a_dstB, coef, mkey, den);
            k_pass3<H><<<edgeWaveBlocks, BT, 0, stream>>>(ei, ea, loop_attr, a_srcB, a_dstB, coef, mkey, den, xw, hout);
            k_epilogue<<<ndBlocks, BT, 0, stream>>>(hout, hin, bias[L]);
        } else {
            constexpr int H = 1;
            k_xw_s<H * DH><<<(NN * H * DH + BT - 1) / BT, BT, 0, stream>>>(hin, lin_W[L], xw);
            k_att_s<H><<<(NN * H + BT - 1) / BT, BT, 0, stream>>>(xw, att_src[L], att_dst[L], a_srcB, a_dstB);
            k_coef_s<H><<<1, 64, 0, stream>>>(edge_W[L], att_edge[L], coef);
            k_init_mden<H><<<(NN * H + BT - 1) / BT, BT, 0, stream>>>(mkey, den);
            k_zero_h<<<ndBlocks, BT, 0, stream>>>(hout);
            k_pass1<H><<<etotBlocks, BT, 0, stream>>>(ei, ea, loop_attr, a_srcB, a_dstB, coef, mkey);
            k_pass2<H><<<etotBlocks, BT, 0, stream>>>(ei, ea, loop_attr, a_srcB, a_dstB, coef, mkey, den);
            k_pass3<H><<<edgeWaveBlocks, BT, 0, stream>>>(ei, ea, loop_attr, a_srcB, a_dstB, coef, mkey, den, xw, hout);
            k_epilogue<<<ndBlocks, BT, 0, stream>>>(hout, hin, bias[L]);
        }
        float* t = hin; hin = hout; hout = t;
    }
    k_head_s<<<nodeBlocks, BT, 0, stream>>>(hin, fc1_W, fc1_b, fc2_W, fc2_b, out);
}

// Round 5
// 2418.861 us; speedup vs baseline: 1.1701x; 1.1701x over previous
//
#include <hip/hip_runtime.h>
#include <math.h>

#define NN 100000
#define NE 1000000
#define DH 64
constexpr int ETOT = NE + NN;

// ---- float <-> monotone-uint encoding for atomic max on floats ----
__device__ inline unsigned f2key(float f) {
    unsigned b = __float_as_uint(f);
    return (b & 0x80000000u) ? ~b : (b | 0x80000000u);
}
__device__ inline float key2f(unsigned k) {
    unsigned b = (k & 0x80000000u) ? (k & 0x7fffffffu) : ~k;
    return __uint_as_float(b);
}

// ---------------- self-loop attr ----------------

__global__ void k_zero_init(int* __restrict__ deg, float* __restrict__ loop_sum) {
    int i = blockIdx.x * blockDim.x + threadIdx.x;
    if (i < NN) {
        deg[i] = 0;
        loop_sum[2 * i] = 0.f;
        loop_sum[2 * i + 1] = 0.f;
    }
}

__global__ void k_deg_loopsum(const int* __restrict__ ei, const float* __restrict__ ea,
                              int* __restrict__ deg, float* __restrict__ loop_sum) {
    int e = blockIdx.x * blockDim.x + threadIdx.x;
    if (e < NE) {
        int d = ei[NE + e];
        atomicAdd(&deg[d], 1);
        atomicAdd(&loop_sum[2 * d], ea[2 * e]);
        atomicAdd(&loop_sum[2 * d + 1], ea[2 * e + 1]);
    }
}

__global__ void k_loop_attr(const int* __restrict__ deg, const float* __restrict__ loop_sum,
                            float* __restrict__ loop_attr) {
    int n = blockIdx.x * blockDim.x + threadIdx.x;
    if (n < NN) {
        float dv = fmaxf((float)deg[n], 1.0f);
        loop_attr[2 * n] = loop_sum[2 * n] / dv;
        loop_attr[2 * n + 1] = loop_sum[2 * n + 1] / dv;
    }
}

// ---------------- encoder: h = relu(x @ enc_W + enc_b) ----------------

__global__ void k_encoder(const float* __restrict__ x, const float* __restrict__ W,
                          const float* __restrict__ b, float* __restrict__ h) {
    int idx = blockIdx.x * blockDim.x + threadIdx.x;
    int n = idx >> 6, d = idx & 63;
    if (n < NN) {
        float v = x[2 * n] * W[d] + x[2 * n + 1] * W[DH + d] + b[d];
        h[idx] = fmaxf(v, 0.f);
    }
}

// ---------------- xw = h @ lin_W, vectorized: 8 outputs per thread ----------------

template <int C>
__global__ void k_xw_v(const float* __restrict__ h, const float* __restrict__ W,
                       float* __restrict__ xw) {
    constexpr int TPN = C / 8;              // threads per node
    int gid = blockIdx.x * blockDim.x + threadIdx.x;
    int n  = gid / TPN;
    int c0 = (gid % TPN) * 8;
    if (n >= NN) return;
    float acc0 = 0.f, acc1 = 0.f, acc2 = 0.f, acc3 = 0.f;
    float acc4 = 0.f, acc5 = 0.f, acc6 = 0.f, acc7 = 0.f;
    const float* hrow = h + (size_t)n * DH;
    const float* wp = W + c0;
#pragma unroll 4
    for (int k = 0; k < DH; k++) {
        float hk = hrow[k];
        const float4* w4 = (const float4*)(wp + (size_t)k * C);
        float4 a = w4[0], b = w4[1];
        acc0 += hk * a.x; acc1 += hk * a.y; acc2 += hk * a.z; acc3 += hk * a.w;
        acc4 += hk * b.x; acc5 += hk * b.y; acc6 += hk * b.z; acc7 += hk * b.w;
    }
    float4* o = (float4*)(xw + (size_t)n * C + c0);
    o[0] = make_float4(acc0, acc1, acc2, acc3);
    o[1] = make_float4(acc4, acc5, acc6, acc7);
}

// ---------------- a_src/a_dst: one thread per (n,h), float4 reads ----------------

template <int H>
__global__ void k_att_s(const float* __restrict__ xw, const float* __restrict__ att_src,
                        const float* __restrict__ att_dst,
                        float* __restrict__ a_src, float* __restrict__ a_dst) {
    int idx = blockIdx.x * blockDim.x + threadIdx.x;
    int n = idx / H, hh = idx % H;
    if (n >= NN) return;
    const float4* xv4 = (const float4*)(xw + (size_t)n * (H * DH) + hh * DH);
    const float4* as4 = (const float4*)(att_src + hh * DH);
    const float4* ad4 = (const float4*)(att_dst + hh * DH);
    float ps = 0.f, pd = 0.f;
    for (int q = 0; q < DH / 4; q++) {
        float4 xv = xv4[q], as = as4[q], ad = ad4[q];
        ps += xv.x * as.x; ps += xv.y * as.y; ps += xv.z * as.z; ps += xv.w * as.w;
        pd += xv.x * ad.x; pd += xv.y * ad.y; pd += xv.z * ad.z; pd += xv.w * ad.w;
    }
    a_src[idx] = ps;
    a_dst[idx] = pd;
}

// ---------------- edge coef ----------------

template <int H>
__global__ void k_coef_s(const float* __restrict__ edge_W, const float* __restrict__ att_edge,
                         float* __restrict__ coef) {
    if (blockIdx.x || threadIdx.x) return;
    for (int w = 0; w < 2; w++)
        for (int h = 0; h < H; h++) {
            float s = 0.f;
            for (int d = 0; d < DH; d++)
                s += edge_W[w * H * DH + h * DH + d] * att_edge[h * DH + d];
            coef[w * H + h] = s;
        }
}

// ---------------- segment softmax over dst ----------------

template <int H>
__global__ void k_init_mden(unsigned* __restrict__ mkey, float* __restrict__ den) {
    int i = blockIdx.x * blockDim.x + threadIdx.x;
    if (i < NN * H) {
        mkey[i] = f2key(-1e30f);
        den[i] = 0.f;
    }
}

__global__ void k_zero_h(float* __restrict__ p) {
    int i = blockIdx.x * blockDim.x + threadIdx.x;
    if (i < NN * DH) p[i] = 0.f;
}

template <int H>
__device__ inline void edge_fields(int e, const int* ei, const float* ea, const float* loop_attr,
                                   int& s, int& d, float& e0, float& e1) {
    if (e < NE) {
        s = ei[e]; d = ei[NE + e];
        e0 = ea[2 * e]; e1 = ea[2 * e + 1];
    } else {
        s = d = e - NE;
        e0 = loop_attr[2 * s]; e1 = loop_attr[2 * s + 1];
    }
}

// pass1: compute logits, store them, atomic segment max
template <int H>
__global__ void k_pass1(const int* __restrict__ ei, const float* __restrict__ ea,
                        const float* __restrict__ loop_attr,
                        const float* __restrict__ a_src, const float* __restrict__ a_dst,
                        const float* __restrict__ coef,
                        float* __restrict__ logits, unsigned* __restrict__ mkey) {
    int e = blockIdx.x * blockDim.x + threadIdx.x;
    if (e >= ETOT) return;
    int s, d; float e0, e1;
    edge_fields<H>(e, ei, ea, loop_attr, s, d, e0, e1);
    for (int h = 0; h < H; h++) {
        float lg = a_src[s * H + h] + a_dst[d * H + h] + e0 * coef[h] + e1 * coef[H + h];
        lg = (lg > 0.f) ? lg : 0.2f * lg;
        logits[(size_t)e * H + h] = lg;
        atomicMax(&mkey[d * H + h], f2key(lg));
    }
}

// pass2: ex = exp(logit - m), store back, atomic segment sum
template <int H>
__global__ void k_pass2(const int* __restrict__ ei, const unsigned* __restrict__ mkey,
                        float* __restrict__ logits, float* __restrict__ den) {
    int e = blockIdx.x * blockDim.x + threadIdx.x;
    if (e >= ETOT) return;
    int d = (e < NE) ? ei[NE + e] : (e - NE);
    for (int h = 0; h < H; h++) {
        float m = key2f(mkey[d * H + h]);
        float ex = __expf(logits[(size_t)e * H + h] - m);
        logits[(size_t)e * H + h] = ex;
        atomicAdd(&den[d * H + h], ex);
    }
}

// pass3: one thread per (edge, dim): alpha = ex/den, gather xw, scatter-add head-mean
template <int H>
__global__ void k_pass3(const int* __restrict__ ei, const float* __restrict__ ex,
                        const float* __restrict__ den, const float* __restrict__ xw,
                        float* __restrict__ acc) {
    long long gid = (long long)blockIdx.x * blockDim.x + threadIdx.x;
    int e = (int)(gid >> 6);
    int dim = (int)(gid & 63);
    if (e >= ETOT) return;
    int s, d;
    if (e < NE) { s = ei[e]; d = ei[NE + e]; }
    else        { s = d = e - NE; }
    float v = 0.f;
    for (int h = 0; h < H; h++) {
        float alpha = ex[(size_t)e * H + h] / (den[d * H + h] + 1e-16f);
        v += alpha * xw[(size_t)s * (H * DH) + h * DH + dim];
    }
    atomicAdd(&acc[d * DH + dim], v * (1.0f / H));
}

__global__ void k_epilogue(float* __restrict__ hout, const float* __restrict__ hin,
                           const float* __restrict__ bias) {
    int idx = blockIdx.x * blockDim.x + threadIdx.x;
    if (idx < NN * DH) {
        float v = hout[idx] + bias[idx & 63];
        hout[idx] = fmaxf(v, 0.f) + hin[idx];
    }
}

// ---------------- final MLP head, scalar: one thread per node ----------------

__global__ void k_head_s(const float* __restrict__ h, const float* __restrict__ fc1_W,
                         const float* __restrict__ fc1_b, const float* __restrict__ fc2_W,
                         const float* __restrict__ fc2_b, float* __restrict__ out) {
    int n = blockIdx.x * blockDim.x + threadIdx.x;
    if (n >= NN) return;
    float y[32];
#pragma unroll
    for (int c = 0; c < 32; c++) y[c] = fc1_b[c];
    for (int k = 0; k < DH; k++) {
        float hk = h[n * DH + k];
#pragma unroll
        for (int c = 0; c < 32; c++) y[c] += hk * fc1_W[k * 32 + c];
    }
    float o0 = fc2_b[0], o1 = fc2_b[1];
#pragma unroll
    for (int c = 0; c < 32; c++) {
        float yr = fmaxf(y[c], 0.f);
        o0 += yr * fc2_W[c * 2];
        o1 += yr * fc2_W[c * 2 + 1];
    }
    out[2 * n] = tanhf(o0);
    out[2 * n + 1] = tanhf(o1);
}

// ---------------- launch ----------------

extern "C" void kernel_launch(void* const* d_in, const int* in_sizes, int n_in,
                              void* d_out, int out_size, void* d_ws, size_t ws_size,
                              hipStream_t stream) {
    const float* x     = (const float*)d_in[0];
    const int*   ei    = (const int*)d_in[1];
    const float* ea    = (const float*)d_in[2];
    const float* enc_W = (const float*)d_in[3];
    const float* enc_b = (const float*)d_in[4];
    const float* lin_W[3]    = {(const float*)d_in[5],  (const float*)d_in[11], (const float*)d_in[17]};
    const float* att_src[3]  = {(const float*)d_in[6],  (const float*)d_in[12], (const float*)d_in[18]};
    const float* att_dst[3]  = {(const float*)d_in[7],  (const float*)d_in[13], (const float*)d_in[19]};
    const float* edge_W[3]   = {(const float*)d_in[8],  (const float*)d_in[14], (const float*)d_in[20]};
    const float* att_edge[3] = {(const float*)d_in[9],  (const float*)d_in[15], (const float*)d_in[21]};
    const float* bias[3]     = {(const float*)d_in[10], (const float*)d_in[16], (const float*)d_in[22]};
    const float* fc1_W = (const float*)d_in[23];
    const float* fc1_b = (const float*)d_in[24];
    const float* fc2_W = (const float*)d_in[25];
    const float* fc2_b = (const float*)d_in[26];
    float* out = (float*)d_out;

    char* p = (char*)d_ws;
    auto alloc = [&](size_t bytes) -> void* {
        void* r = (void*)p;
        p += (bytes + 255) & ~(size_t)255;
        return r;
    };
    int*      deg       = (int*)alloc((size_t)NN * 4);
    float*    loop_sum  = (float*)alloc((size_t)NN * 8);
    float*    loop_attr = (float*)alloc((size_t)NN * 8);
    float*    a_srcB    = (float*)alloc((size_t)NN * 4 * 4);
    float*    a_dstB    = (float*)alloc((size_t)NN * 4 * 4);
    float*    coef      = (float*)alloc(256);
    unsigned* mkey      = (unsigned*)alloc((size_t)NN * 4 * 4);
    float*    den       = (float*)alloc((size_t)NN * 4 * 4);
    float*    logits    = (float*)alloc((size_t)ETOT * 4 * 4);
    float*    xw        = (float*)alloc((size_t)NN * 256 * 4);
    float*    hA        = (float*)alloc((size_t)NN * DH * 4);
    float*    hB        = (float*)alloc((size_t)NN * DH * 4);

    const int BT = 256;
    const int nodeBlocks = (NN + BT - 1) / BT;
    const int edgeBlocks = (NE + BT - 1) / BT;
    const int etotBlocks = (ETOT + BT - 1) / BT;
    const int ndBlocks   = (NN * DH + BT - 1) / BT;
    const int edgeWaveBlocks = (int)(((long long)ETOT * 64 + BT - 1) / BT);

    k_zero_init<<<nodeBlocks, BT, 0, stream>>>(deg, loop_sum);
    k_deg_loopsum<<<edgeBlocks, BT, 0, stream>>>(ei, ea, deg, loop_sum);
    k_loop_attr<<<nodeBlocks, BT, 0, stream>>>(deg, loop_sum, loop_attr);
    k_encoder<<<ndBlocks, BT, 0, stream>>>(x, enc_W, enc_b, hA);

    float* hin = hA;
    float* hout = hB;

    for (int L = 0; L < 3; L++) {
        if (L < 2) {
            constexpr int H = 4;
            constexpr int C = H * DH;
            k_xw_v<C><<<(NN * (C / 8) + BT - 1) / BT, BT, 0, stream>>>(hin, lin_W[L], xw);
            k_att_s<H><<<(NN * H + BT - 1) / BT, BT, 0, stream>>>(xw, att_src[L], att_dst[L], a_srcB, a_dstB);
            k_coef_s<H><<<1, 64, 0, stream>>>(edge_W[L], att_edge[L], coef);
            k_init_mden<H><<<(NN * H + BT - 1) / BT, BT, 0, stream>>>(mkey, den);
            k_zero_h<<<ndBlocks, BT, 0, stream>>>(hout);
            k_pass1<H><<<etotBlocks, BT, 0, stream>>>(ei, ea, loop_attr, a_srcB, a_dstB, coef, logits, mkey);
            k_pass2<H><<<etotBlocks, BT, 0, stream>>>(ei, mkey, logits, den);
            k_pass3<H><<<edgeWaveBlocks, BT, 0, stream>>>(ei, logits, den, xw, hout);
            k_epilogue<<<ndBlocks, BT, 0, stream>>>(hout, hin, bias[L]);
        } else {
            constexpr int H = 1;
            constexpr int C = H * DH;
            k_xw_v<C><<<(NN * (C / 8) + BT - 1) / BT, BT, 0, stream>>>(hin, lin_W[L], xw);
            k_att_s<H><<<(NN * H + BT - 1) / BT, BT, 0, stream>>>(xw, att_src[L], att_dst[L], a_srcB, a_dstB);
            k_coef_s<H><<<1, 64, 0, stream>>>(edge_W[L], att_edge[L], coef);
            k_init_mden<H><<<(NN * H + BT - 1) / BT, BT, 0, stream>>>(mkey, den);
            k_zero_h<<<ndBlocks, BT, 0, stream>>>(hout);
            k_pass1<H><<<etotBlocks, BT, 0, stream>>>(ei, ea, loop_attr, a_srcB, a_dstB, coef, logits, mkey);
            k_pass2<H><<<etotBlocks, BT, 0, stream>>>(ei, mkey, logits, den);
            k_pass3<H><<<edgeWaveBlocks, BT, 0, stream>>>(ei, logits, den, xw, hout);
            k_epilogue<<<ndBlocks, BT, 0, stream>>>(hout, hin, bias[L]);
        }
        float* t = hin; hin = hout; hout = t;
    }
    k_head_s<<<nodeBlocks, BT, 0, stream>>>(hin, fc1_W, fc1_b, fc2_W, fc2_b, out);
}

// Round 6
// 1449.603 us; speedup vs baseline: 1.9524x; 1.6686x over previous
//
#include <hip/hip_runtime.h>
#include <math.h>

#define NN 100000
#define NE 1000000
#define DH 64
constexpr int ETOT = NE + NN;
constexpr int CHUNK = 100;
constexpr int NCHUNK = (NN + CHUNK - 1) / CHUNK;   // 1000

// ---------------- degree + self-loop attr sums ----------------

__global__ void k_zero_init(int* __restrict__ deg, float* __restrict__ loop_sum) {
    int i = blockIdx.x * blockDim.x + threadIdx.x;
    if (i < NN) {
        deg[i] = 0;
        loop_sum[2 * i] = 0.f;
        loop_sum[2 * i + 1] = 0.f;
    }
}

__global__ void k_deg_loopsum(const int* __restrict__ ei, const float* __restrict__ ea,
                              int* __restrict__ deg, float* __restrict__ loop_sum) {
    int e = blockIdx.x * blockDim.x + threadIdx.x;
    if (e < NE) {
        int d = ei[NE + e];
        atomicAdd(&deg[d], 1);
        atomicAdd(&loop_sum[2 * d], ea[2 * e]);
        atomicAdd(&loop_sum[2 * d + 1], ea[2 * e + 1]);
    }
}

// ---------------- chunked prefix scan (scalar, no LDS/shuffle) ----------------

__global__ void k_scan_a(const int* __restrict__ deg, int* __restrict__ part) {
    int c = blockIdx.x * blockDim.x + threadIdx.x;
    if (c >= NCHUNK) return;
    int lo = c * CHUNK;
    int hi = lo + CHUNK; if (hi > NN) hi = NN;
    int s = 0;
    for (int i = lo; i < hi; i++) s += deg[i];
    part[c] = s;
}

__global__ void k_scan_b(int* __restrict__ part) {
    if (threadIdx.x || blockIdx.x) return;
    int run = 0;
    for (int i = 0; i < NCHUNK; i++) { int t = part[i]; part[i] = run; run += t; }
}

__global__ void k_scan_c(const int* __restrict__ deg, const int* __restrict__ part,
                         int* __restrict__ row, int* __restrict__ cursor) {
    int c = blockIdx.x * blockDim.x + threadIdx.x;
    if (c >= NCHUNK) return;
    int lo = c * CHUNK;
    int hi = lo + CHUNK; if (hi > NN) hi = NN;
    int run = part[c];
    for (int i = lo; i < hi; i++) {
        int r = run + i;              // prefix_deg(i) + i self-loop slots before node i
        row[i] = r;
        cursor[i] = r;
        run += deg[i];
    }
    if (c == NCHUNK - 1) row[NN] = run + NN;   // = NE + NN
}

__global__ void k_fill_csr(const int* __restrict__ ei, const float* __restrict__ ea,
                           int* __restrict__ cursor, int* __restrict__ csr_src,
                           float* __restrict__ csr_ea) {
    int e = blockIdx.x * blockDim.x + threadIdx.x;
    if (e < NE) {
        int s = ei[e];
        int d = ei[NE + e];
        int pos = atomicAdd(&cursor[d], 1);
        csr_src[pos] = s;
        csr_ea[2 * pos] = ea[2 * e];
        csr_ea[2 * pos + 1] = ea[2 * e + 1];
    }
}

__global__ void k_fill_self(const int* __restrict__ deg, const int* __restrict__ row,
                            const float* __restrict__ loop_sum,
                            int* __restrict__ csr_src, float* __restrict__ csr_ea) {
    int n = blockIdx.x * blockDim.x + threadIdx.x;
    if (n < NN) {
        int pos = row[n] + deg[n];    // last slot of segment
        csr_src[pos] = n;
        float dv = fmaxf((float)deg[n], 1.0f);
        csr_ea[2 * pos] = loop_sum[2 * n] / dv;
        csr_ea[2 * pos + 1] = loop_sum[2 * n + 1] / dv;
    }
}

// ---------------- encoder: h = relu(x @ enc_W + enc_b) ----------------

__global__ void k_encoder(const float* __restrict__ x, const float* __restrict__ W,
                          const float* __restrict__ b, float* __restrict__ h) {
    int idx = blockIdx.x * blockDim.x + threadIdx.x;
    int n = idx >> 6, d = idx & 63;
    if (n < NN) {
        float v = x[2 * n] * W[d] + x[2 * n + 1] * W[DH + d] + b[d];
        h[idx] = fmaxf(v, 0.f);
    }
}

// ---------------- xw = h @ lin_W, vectorized: 8 outputs per thread ----------------

template <int C>
__global__ void k_xw_v(const float* __restrict__ h, const float* __restrict__ W,
                       float* __restrict__ xw) {
    constexpr int TPN = C / 8;
    int gid = blockIdx.x * blockDim.x + threadIdx.x;
    int n  = gid / TPN;
    int c0 = (gid % TPN) * 8;
    if (n >= NN) return;
    float acc0 = 0.f, acc1 = 0.f, acc2 = 0.f, acc3 = 0.f;
    float acc4 = 0.f, acc5 = 0.f, acc6 = 0.f, acc7 = 0.f;
    const float* hrow = h + (size_t)n * DH;
    const float* wp = W + c0;
#pragma unroll 4
    for (int k = 0; k < DH; k++) {
        float hk = hrow[k];
        const float4* w4 = (const float4*)(wp + (size_t)k * C);
        float4 a = w4[0], b = w4[1];
        acc0 += hk * a.x; acc1 += hk * a.y; acc2 += hk * a.z; acc3 += hk * a.w;
        acc4 += hk * b.x; acc5 += hk * b.y; acc6 += hk * b.z; acc7 += hk * b.w;
    }
    float4* o = (float4*)(xw + (size_t)n * C + c0);
    o[0] = make_float4(acc0, acc1, acc2, acc3);
    o[1] = make_float4(acc4, acc5, acc6, acc7);
}

// ---------------- a_src/a_dst: one thread per (n,h), float4 reads ----------------

template <int H>
__global__ void k_att_s(const float* __restrict__ xw, const float* __restrict__ att_src,
                        const float* __restrict__ att_dst,
                        float* __restrict__ a_src, float* __restrict__ a_dst) {
    int idx = blockIdx.x * blockDim.x + threadIdx.x;
    int n = idx / H, hh = idx % H;
    if (n >= NN) return;
    const float4* xv4 = (const float4*)(xw + (size_t)n * (H * DH) + hh * DH);
    const float4* as4 = (const float4*)(att_src + hh * DH);
    const float4* ad4 = (const float4*)(att_dst + hh * DH);
    float ps = 0.f, pd = 0.f;
    for (int q = 0; q < DH / 4; q++) {
        float4 xv = xv4[q], as = as4[q], ad = ad4[q];
        ps += xv.x * as.x; ps += xv.y * as.y; ps += xv.z * as.z; ps += xv.w * as.w;
        pd += xv.x * ad.x; pd += xv.y * ad.y; pd += xv.z * ad.z; pd += xv.w * ad.w;
    }
    a_src[idx] = ps;
    a_dst[idx] = pd;
}

// ---------------- edge coef ----------------

template <int H>
__global__ void k_coef_s(const float* __restrict__ edge_W, const float* __restrict__ att_edge,
                         float* __restrict__ coef) {
    if (blockIdx.x || threadIdx.x) return;
    for (int w = 0; w < 2; w++)
        for (int h = 0; h < H; h++) {
            float s = 0.f;
            for (int d = 0; d < DH; d++)
                s += edge_W[w * H * DH + h * DH + d] * att_edge[h * DH + d];
            coef[w * H + h] = s;
        }
}

// ---------------- per-node m, den: one THREAD per node, serial, no atomics ----------------

template <int H>
__device__ inline float logit_of(const float* __restrict__ a_src, const float* ad,
                                 const float* cf, int s, float e0, float e1, int h) {
    float lg = a_src[s * H + h] + ad[h] + e0 * cf[h] + e1 * cf[H + h];
    return (lg > 0.f) ? lg : 0.2f * lg;
}

template <int H>
__global__ void k_mden(const int* __restrict__ row, const int* __restrict__ csr_src,
                       const float* __restrict__ csr_ea, const float* __restrict__ a_src,
                       const float* __restrict__ a_dst, const float* __restrict__ coef,
                       float* __restrict__ mout, float* __restrict__ denout) {
    int n = blockIdx.x * blockDim.x + threadIdx.x;
    if (n >= NN) return;
    int r0 = row[n], r1 = row[n + 1];
    float ad[H], cf[2 * H], m[H], den[H];
#pragma unroll
    for (int h = 0; h < H; h++) { ad[h] = a_dst[n * H + h]; m[h] = -1e30f; den[h] = 0.f; }
#pragma unroll
    for (int i = 0; i < 2 * H; i++) cf[i] = coef[i];
    for (int j = r0; j < r1; j++) {
        int s = csr_src[j];
        float e0 = csr_ea[2 * j], e1 = csr_ea[2 * j + 1];
#pragma unroll
        for (int h = 0; h < H; h++) {
            float lg = logit_of<H>(a_src, ad, cf, s, e0, e1, h);
            m[h] = fmaxf(m[h], lg);
        }
    }
    for (int j = r0; j < r1; j++) {
        int s = csr_src[j];
        float e0 = csr_ea[2 * j], e1 = csr_ea[2 * j + 1];
#pragma unroll
        for (int h = 0; h < H; h++) {
            float lg = logit_of<H>(a_src, ad, cf, s, e0, e1, h);
            den[h] += __expf(lg - m[h]);
        }
    }
#pragma unroll
    for (int h = 0; h < H; h++) { mout[n * H + h] = m[h]; denout[n * H + h] = den[h]; }
}

// ---------------- aggregate: one WAVE per node, lane = dim, register accum ----------------

template <int H>
__global__ void k_agg(const int* __restrict__ row, const int* __restrict__ csr_src,
                      const float* __restrict__ csr_ea, const float* __restrict__ a_src,
                      const float* __restrict__ a_dst, const float* __restrict__ coef,
                      const float* __restrict__ mden_m, const float* __restrict__ mden_d,
                      const float* __restrict__ xw, const float* __restrict__ bias,
                      const float* __restrict__ hin, float* __restrict__ hout) {
    int gid = blockIdx.x * blockDim.x + threadIdx.x;
    int n = gid >> 6;
    int lane = gid & 63;
    if (n >= NN) return;
    int r0 = row[n], r1 = row[n + 1];
    float ad[H], cf[2 * H], m[H], inv[H], acc[H];
#pragma unroll
    for (int h = 0; h < H; h++) {
        ad[h]  = a_dst[n * H + h];
        m[h]   = mden_m[n * H + h];
        inv[h] = 1.f / (mden_d[n * H + h] + 1e-16f);
        acc[h] = 0.f;
    }
#pragma unroll
    for (int i = 0; i < 2 * H; i++) cf[i] = coef[i];
    for (int j = r0; j < r1; j++) {
        int s = csr_src[j];                      // wave-uniform broadcast load
        float e0 = csr_ea[2 * j], e1 = csr_ea[2 * j + 1];
        const float* xp = xw + (size_t)s * (H * DH) + lane;
#pragma unroll
        for (int h = 0; h < H; h++) {
            float lg = logit_of<H>(a_src, ad, cf, s, e0, e1, h);
            float ex = __expf(lg - m[h]);
            acc[h] += ex * xp[h * DH];           // 256B coalesced gather per (edge,h)
        }
    }
    float val = 0.f;
#pragma unroll
    for (int h = 0; h < H; h++) val += acc[h] * inv[h];
    val *= (1.0f / H);
    val += bias[lane];
    val = fmaxf(val, 0.f);
    hout[n * DH + lane] = val + hin[n * DH + lane];
}

// ---------------- final MLP head, scalar: one thread per node ----------------

__global__ void k_head_s(const float* __restrict__ h, const float* __restrict__ fc1_W,
                         const float* __restrict__ fc1_b, const float* __restrict__ fc2_W,
                         const float* __restrict__ fc2_b, float* __restrict__ out) {
    int n = blockIdx.x * blockDim.x + threadIdx.x;
    if (n >= NN) return;
    float y[32];
#pragma unroll
    for (int c = 0; c < 32; c++) y[c] = fc1_b[c];
    for (int k = 0; k < DH; k++) {
        float hk = h[n * DH + k];
#pragma unroll
        for (int c = 0; c < 32; c++) y[c] += hk * fc1_W[k * 32 + c];
    }
    float o0 = fc2_b[0], o1 = fc2_b[1];
#pragma unroll
    for (int c = 0; c < 32; c++) {
        float yr = fmaxf(y[c], 0.f);
        o0 += yr * fc2_W[c * 2];
        o1 += yr * fc2_W[c * 2 + 1];
    }
    out[2 * n] = tanhf(o0);
    out[2 * n + 1] = tanhf(o1);
}

// ---------------- launch ----------------

extern "C" void kernel_launch(void* const* d_in, const int* in_sizes, int n_in,
                              void* d_out, int out_size, void* d_ws, size_t ws_size,
                              hipStream_t stream) {
    const float* x     = (const float*)d_in[0];
    const int*   ei    = (const int*)d_in[1];
    const float* ea    = (const float*)d_in[2];
    const float* enc_W = (const float*)d_in[3];
    const float* enc_b = (const float*)d_in[4];
    const float* lin_W[3]    = {(const float*)d_in[5],  (const float*)d_in[11], (const float*)d_in[17]};
    const float* att_src[3]  = {(const float*)d_in[6],  (const float*)d_in[12], (const float*)d_in[18]};
    const float* att_dst[3]  = {(const float*)d_in[7],  (const float*)d_in[13], (const float*)d_in[19]};
    const float* edge_W[3]   = {(const float*)d_in[8],  (const float*)d_in[14], (const float*)d_in[20]};
    const float* att_edge[3] = {(const float*)d_in[9],  (const float*)d_in[15], (const float*)d_in[21]};
    const float* bias[3]     = {(const float*)d_in[10], (const float*)d_in[16], (const float*)d_in[22]};
    const float* fc1_W = (const float*)d_in[23];
    const float* fc1_b = (const float*)d_in[24];
    const float* fc2_W = (const float*)d_in[25];
    const float* fc2_b = (const float*)d_in[26];
    float* out = (float*)d_out;

    char* p = (char*)d_ws;
    auto alloc = [&](size_t bytes) -> void* {
        void* r = (void*)p;
        p += (bytes + 255) & ~(size_t)255;
        return r;
    };
    int*   deg      = (int*)alloc((size_t)NN * 4);
    float* loop_sum = (float*)alloc((size_t)NN * 8);
    int*   part     = (int*)alloc((size_t)NCHUNK * 4);
    int*   row      = (int*)alloc((size_t)(NN + 1) * 4);
    int*   cursor   = (int*)alloc((size_t)NN * 4);
    int*   csr_src  = (int*)alloc((size_t)ETOT * 4);
    float* csr_ea   = (float*)alloc((size_t)ETOT * 8);
    float* a_srcB   = (float*)alloc((size_t)NN * 4 * 4);
    float* a_dstB   = (float*)alloc((size_t)NN * 4 * 4);
    float* coef     = (float*)alloc(256);
    float* mdenM    = (float*)alloc((size_t)NN * 4 * 4);
    float* mdenD    = (float*)alloc((size_t)NN * 4 * 4);
    float* xw       = (float*)alloc((size_t)NN * 256 * 4);
    float* hA       = (float*)alloc((size_t)NN * DH * 4);
    float* hB       = (float*)alloc((size_t)NN * DH * 4);

    const int BT = 256;
    const int nodeBlocks  = (NN + BT - 1) / BT;
    const int edgeBlocks  = (NE + BT - 1) / BT;
    const int chunkBlocks = (NCHUNK + BT - 1) / BT;
    const int ndBlocks    = (NN * DH + BT - 1) / BT;
    const int nodeWaveBlocks = (NN * 64 + BT - 1) / BT;

    k_zero_init<<<nodeBlocks, BT, 0, stream>>>(deg, loop_sum);
    k_deg_loopsum<<<edgeBlocks, BT, 0, stream>>>(ei, ea, deg, loop_sum);
    k_scan_a<<<chunkBlocks, BT, 0, stream>>>(deg, part);
    k_scan_b<<<1, 64, 0, stream>>>(part);
    k_scan_c<<<chunkBlocks, BT, 0, stream>>>(deg, part, row, cursor);
    k_fill_csr<<<edgeBlocks, BT, 0, stream>>>(ei, ea, cursor, csr_src, csr_ea);
    k_fill_self<<<nodeBlocks, BT, 0, stream>>>(deg, row, loop_sum, csr_src, csr_ea);
    k_encoder<<<ndBlocks, BT, 0, stream>>>(x, enc_W, enc_b, hA);

    float* hin = hA;
    float* hout = hB;

    for (int L = 0; L < 3; L++) {
        if (L < 2) {
            constexpr int H = 4;
            constexpr int C = H * DH;
            k_xw_v<C><<<(NN * (C / 8) + BT - 1) / BT, BT, 0, stream>>>(hin, lin_W[L], xw);
            k_att_s<H><<<(NN * H + BT - 1) / BT, BT, 0, stream>>>(xw, att_src[L], att_dst[L], a_srcB, a_dstB);
            k_coef_s<H><<<1, 64, 0, stream>>>(edge_W[L], att_edge[L], coef);
            k_mden<H><<<nodeBlocks, BT, 0, stream>>>(row, csr_src, csr_ea, a_srcB, a_dstB, coef, mdenM, mdenD);
            k_agg<H><<<nodeWaveBlocks, BT, 0, stream>>>(row, csr_src, csr_ea, a_srcB, a_dstB, coef,
                                                       mdenM, mdenD, xw, bias[L], hin, hout);
        } else {
            constexpr int H = 1;
            constexpr int C = H * DH;
            k_xw_v<C><<<(NN * (C / 8) + BT - 1) / BT, BT, 0, stream>>>(hin, lin_W[L], xw);
            k_att_s<H><<<(NN * H + BT - 1) / BT, BT, 0, stream>>>(xw, att_src[L], att_dst[L], a_srcB, a_dstB);
            k_coef_s<H><<<1, 64, 0, stream>>>(edge_W[L], att_edge[L], coef);
            k_mden<H><<<nodeBlocks, BT, 0, stream>>>(row, csr_src, csr_ea, a_srcB, a_dstB, coef, mdenM, mdenD);
            k_agg<H><<<nodeWaveBlocks, BT, 0, stream>>>(row, csr_src, csr_ea, a_srcB, a_dstB, coef,
                                                       mdenM, mdenD, xw, bias[L], hin, hout);
        }
        float* t = hin; hin = hout; hout = t;
    }
    k_head_s<<<nodeBlocks, BT, 0, stream>>>(hin, fc1_W, fc1_b, fc2_W, fc2_b, out);
}

// Round 7
// 1190.593 us; speedup vs baseline: 2.3772x; 1.2175x over previous
//
#include <hip/hip_runtime.h>
#include <math.h>

#define NN 100000
#define NE 1000000
#define DH 64
constexpr int ETOT = NE + NN;
constexpr int CHUNK = 100;
constexpr int NCHUNK = (NN + CHUNK - 1) / CHUNK;   // 1000

// ---------------- degree + self-loop attr sums ----------------

__global__ void k_zero_init(int* __restrict__ deg, float* __restrict__ loop_sum) {
    int i = blockIdx.x * blockDim.x + threadIdx.x;
    if (i < NN) {
        deg[i] = 0;
        loop_sum[2 * i] = 0.f;
        loop_sum[2 * i + 1] = 0.f;
    }
}

__global__ void k_deg_loopsum(const int* __restrict__ ei, const float* __restrict__ ea,
                              int* __restrict__ deg, float* __restrict__ loop_sum) {
    int e = blockIdx.x * blockDim.x + threadIdx.x;
    if (e < NE) {
        int d = ei[NE + e];
        atomicAdd(&deg[d], 1);
        atomicAdd(&loop_sum[2 * d], ea[2 * e]);
        atomicAdd(&loop_sum[2 * d + 1], ea[2 * e + 1]);
    }
}

// ---------------- chunked prefix scan (scalar, no LDS/shuffle) ----------------

__global__ void k_scan_a(const int* __restrict__ deg, int* __restrict__ part) {
    int c = blockIdx.x * blockDim.x + threadIdx.x;
    if (c >= NCHUNK) return;
    int lo = c * CHUNK;
    int hi = lo + CHUNK; if (hi > NN) hi = NN;
    int s = 0;
    for (int i = lo; i < hi; i++) s += deg[i];
    part[c] = s;
}

__global__ void k_scan_b(int* __restrict__ part) {
    if (threadIdx.x || blockIdx.x) return;
    int run = 0;
    for (int i = 0; i < NCHUNK; i++) { int t = part[i]; part[i] = run; run += t; }
}

__global__ void k_scan_c(const int* __restrict__ deg, const int* __restrict__ part,
                         int* __restrict__ row, int* __restrict__ cursor) {
    int c = blockIdx.x * blockDim.x + threadIdx.x;
    if (c >= NCHUNK) return;
    int lo = c * CHUNK;
    int hi = lo + CHUNK; if (hi > NN) hi = NN;
    int run = part[c];
    for (int i = lo; i < hi; i++) {
        int r = run + i;              // prefix_deg(i) + i self-loop slots before node i
        row[i] = r;
        cursor[i] = r;
        run += deg[i];
    }
    if (c == NCHUNK - 1) row[NN] = run + NN;   // = NE + NN
}

__global__ void k_fill_csr(const int* __restrict__ ei, const float* __restrict__ ea,
                           int* __restrict__ cursor, int* __restrict__ csr_src,
                           float* __restrict__ csr_ea) {
    int e = blockIdx.x * blockDim.x + threadIdx.x;
    if (e < NE) {
        int s = ei[e];
        int d = ei[NE + e];
        int pos = atomicAdd(&cursor[d], 1);
        csr_src[pos] = s;
        csr_ea[2 * pos] = ea[2 * e];
        csr_ea[2 * pos + 1] = ea[2 * e + 1];
    }
}

__global__ void k_fill_self(const int* __restrict__ deg, const int* __restrict__ row,
                            const float* __restrict__ loop_sum,
                            int* __restrict__ csr_src, float* __restrict__ csr_ea) {
    int n = blockIdx.x * blockDim.x + threadIdx.x;
    if (n < NN) {
        int pos = row[n] + deg[n];    // last slot of segment
        csr_src[pos] = n;
        float dv = fmaxf((float)deg[n], 1.0f);
        csr_ea[2 * pos] = loop_sum[2 * n] / dv;
        csr_ea[2 * pos + 1] = loop_sum[2 * n + 1] / dv;
    }
}

// ---------------- encoder: h = relu(x @ enc_W + enc_b) ----------------

__global__ void k_encoder(const float* __restrict__ x, const float* __restrict__ W,
                          const float* __restrict__ b, float* __restrict__ h) {
    int idx = blockIdx.x * blockDim.x + threadIdx.x;
    int n = idx >> 6, d = idx & 63;
    if (n < NN) {
        float v = x[2 * n] * W[d] + x[2 * n + 1] * W[DH + d] + b[d];
        h[idx] = fmaxf(v, 0.f);
    }
}

// ---------------- xw = h @ lin_W, register-blocked: 4 nodes x 8 cols per thread ----------------

template <int C>
__global__ void k_xw_v4(const float* __restrict__ h, const float* __restrict__ W,
                        float* __restrict__ xw) {
    constexpr int TPN = C / 8;              // col-group threads per node-block
    int gid = blockIdx.x * blockDim.x + threadIdx.x;
    int nb = gid / TPN;                     // block of 4 nodes (NN % 4 == 0)
    int c0 = (gid % TPN) * 8;
    if (nb >= NN / 4) return;
    int n0 = nb * 4;
    const float* hrow = h + (size_t)n0 * DH;
    const float* wp = W + c0;
    float acc[4][8];
#pragma unroll
    for (int i = 0; i < 4; i++)
#pragma unroll
        for (int j = 0; j < 8; j++) acc[i][j] = 0.f;
    for (int q = 0; q < DH / 4; q++) {
        float hreg[4][4];
#pragma unroll
        for (int i = 0; i < 4; i++) {
            float4 v = *(const float4*)(hrow + i * DH + q * 4);
            hreg[i][0] = v.x; hreg[i][1] = v.y; hreg[i][2] = v.z; hreg[i][3] = v.w;
        }
#pragma unroll
        for (int t = 0; t < 4; t++) {
            int k = q * 4 + t;
            const float4* w4 = (const float4*)(wp + (size_t)k * C);
            float4 a = w4[0], b = w4[1];
            float wv[8] = {a.x, a.y, a.z, a.w, b.x, b.y, b.z, b.w};
#pragma unroll
            for (int i = 0; i < 4; i++) {
                float hk = hreg[i][t];
#pragma unroll
                for (int j = 0; j < 8; j++) acc[i][j] += hk * wv[j];
            }
        }
    }
#pragma unroll
    for (int i = 0; i < 4; i++) {
        float4* o = (float4*)(xw + (size_t)(n0 + i) * C + c0);
        o[0] = make_float4(acc[i][0], acc[i][1], acc[i][2], acc[i][3]);
        o[1] = make_float4(acc[i][4], acc[i][5], acc[i][6], acc[i][7]);
    }
}

// ---------------- a_src/a_dst: one thread per (n,h), float4 reads ----------------

template <int H>
__global__ void k_att_s(const float* __restrict__ xw, const float* __restrict__ att_src,
                        const float* __restrict__ att_dst,
                        float* __restrict__ a_src, float* __restrict__ a_dst) {
    int idx = blockIdx.x * blockDim.x + threadIdx.x;
    int n = idx / H, hh = idx % H;
    if (n >= NN) return;
    const float4* xv4 = (const float4*)(xw + (size_t)n * (H * DH) + hh * DH);
    const float4* as4 = (const float4*)(att_src + hh * DH);
    const float4* ad4 = (const float4*)(att_dst + hh * DH);
    float ps = 0.f, pd = 0.f;
    for (int q = 0; q < DH / 4; q++) {
        float4 xv = xv4[q], as = as4[q], ad = ad4[q];
        ps += xv.x * as.x; ps += xv.y * as.y; ps += xv.z * as.z; ps += xv.w * as.w;
        pd += xv.x * ad.x; pd += xv.y * ad.y; pd += xv.z * ad.z; pd += xv.w * ad.w;
    }
    a_src[idx] = ps;
    a_dst[idx] = pd;
}

// ---------------- edge coef ----------------

template <int H>
__global__ void k_coef_s(const float* __restrict__ edge_W, const float* __restrict__ att_edge,
                         float* __restrict__ coef) {
    if (blockIdx.x || threadIdx.x) return;
    for (int w = 0; w < 2; w++)
        for (int h = 0; h < H; h++) {
            float s = 0.f;
            for (int d = 0; d < DH; d++)
                s += edge_W[w * H * DH + h * DH + d] * att_edge[h * DH + d];
            coef[w * H + h] = s;
        }
}

// ---------------- per-node m, den: one THREAD per node, serial, no atomics ----------------

template <int H>
__device__ inline float logit_of(const float* __restrict__ a_src, const float* ad,
                                 const float* cf, int s, float e0, float e1, int h) {
    float lg = a_src[s * H + h] + ad[h] + e0 * cf[h] + e1 * cf[H + h];
    return (lg > 0.f) ? lg : 0.2f * lg;
}

template <int H>
__global__ void k_mden(const int* __restrict__ row, const int* __restrict__ csr_src,
                       const float* __restrict__ csr_ea, const float* __restrict__ a_src,
                       const float* __restrict__ a_dst, const float* __restrict__ coef,
                       float* __restrict__ mout, float* __restrict__ denout) {
    int n = blockIdx.x * blockDim.x + threadIdx.x;
    if (n >= NN) return;
    int r0 = row[n], r1 = row[n + 1];
    float ad[H], cf[2 * H], m[H], den[H];
#pragma unroll
    for (int h = 0; h < H; h++) { ad[h] = a_dst[n * H + h]; m[h] = -1e30f; den[h] = 0.f; }
#pragma unroll
    for (int i = 0; i < 2 * H; i++) cf[i] = coef[i];
    for (int j = r0; j < r1; j++) {
        int s = csr_src[j];
        float e0 = csr_ea[2 * j], e1 = csr_ea[2 * j + 1];
#pragma unroll
        for (int h = 0; h < H; h++) {
            float lg = logit_of<H>(a_src, ad, cf, s, e0, e1, h);
            m[h] = fmaxf(m[h], lg);
        }
    }
    for (int j = r0; j < r1; j++) {
        int s = csr_src[j];
        float e0 = csr_ea[2 * j], e1 = csr_ea[2 * j + 1];
#pragma unroll
        for (int h = 0; h < H; h++) {
            float lg = logit_of<H>(a_src, ad, cf, s, e0, e1, h);
            den[h] += __expf(lg - m[h]);
        }
    }
#pragma unroll
    for (int h = 0; h < H; h++) { mout[n * H + h] = m[h]; denout[n * H + h] = den[h]; }
}

// ---------------- aggregate: one WAVE per node, lane = dim, register accum ----------------

template <int H>
__global__ void k_agg(const int* __restrict__ row, const int* __restrict__ csr_src,
                      const float* __restrict__ csr_ea, const float* __restrict__ a_src,
                      const float* __restrict__ a_dst, const float* __restrict__ coef,
                      const float* __restrict__ mden_m, const float* __restrict__ mden_d,
                      const float* __restrict__ xw, const float* __restrict__ bias,
                      const float* __restrict__ hin, float* __restrict__ hout) {
    int gid = blockIdx.x * blockDim.x + threadIdx.x;
    int n = gid >> 6;
    int lane = gid & 63;
    if (n >= NN) return;
    int r0 = row[n], r1 = row[n + 1];
    float ad[H], cf[2 * H], m[H], inv[H], acc[H];
#pragma unroll
    for (int h = 0; h < H; h++) {
        ad[h]  = a_dst[n * H + h];
        m[h]   = mden_m[n * H + h];
        inv[h] = 1.f / (mden_d[n * H + h] + 1e-16f);
        acc[h] = 0.f;
    }
#pragma unroll
    for (int i = 0; i < 2 * H; i++) cf[i] = coef[i];
    for (int j = r0; j < r1; j++) {
        int s = csr_src[j];                      // wave-uniform broadcast load
        float e0 = csr_ea[2 * j], e1 = csr_ea[2 * j + 1];
        const float* xp = xw + (size_t)s * (H * DH) + lane;
#pragma unroll
        for (int h = 0; h < H; h++) {
            float lg = logit_of<H>(a_src, ad, cf, s, e0, e1, h);
            float ex = __expf(lg - m[h]);
            acc[h] += ex * xp[h * DH];           // 256B coalesced gather per (edge,h)
        }
    }
    float val = 0.f;
#pragma unroll
    for (int h = 0; h < H; h++) val += acc[h] * inv[h];
    val *= (1.0f / H);
    val += bias[lane];
    val = fmaxf(val, 0.f);
    hout[n * DH + lane] = val + hin[n * DH + lane];
}

// ---------------- final MLP head, scalar: one thread per node ----------------

__global__ void k_head_s(const float* __restrict__ h, const float* __restrict__ fc1_W,
                         const float* __restrict__ fc1_b, const float* __restrict__ fc2_W,
                         const float* __restrict__ fc2_b, float* __restrict__ out) {
    int n = blockIdx.x * blockDim.x + threadIdx.x;
    if (n >= NN) return;
    float y[32];
#pragma unroll
    for (int c = 0; c < 32; c++) y[c] = fc1_b[c];
    for (int k = 0; k < DH; k++) {
        float hk = h[n * DH + k];
#pragma unroll
        for (int c = 0; c < 32; c++) y[c] += hk * fc1_W[k * 32 + c];
    }
    float o0 = fc2_b[0], o1 = fc2_b[1];
#pragma unroll
    for (int c = 0; c < 32; c++) {
        float yr = fmaxf(y[c], 0.f);
        o0 += yr * fc2_W[c * 2];
        o1 += yr * fc2_W[c * 2 + 1];
    }
    out[2 * n] = tanhf(o0);
    out[2 * n + 1] = tanhf(o1);
}

// ---------------- launch ----------------

extern "C" void kernel_launch(void* const* d_in, const int* in_sizes, int n_in,
                              void* d_out, int out_size, void* d_ws, size_t ws_size,
                              hipStream_t stream) {
    const float* x     = (const float*)d_in[0];
    const int*   ei    = (const int*)d_in[1];
    const float* ea    = (const float*)d_in[2];
    const float* enc_W = (const float*)d_in[3];
    const float* enc_b = (const float*)d_in[4];
    const float* lin_W[3]    = {(const float*)d_in[5],  (const float*)d_in[11], (const float*)d_in[17]};
    const float* att_src[3]  = {(const float*)d_in[6],  (const float*)d_in[12], (const float*)d_in[18]};
    const float* att_dst[3]  = {(const float*)d_in[7],  (const float*)d_in[13], (const float*)d_in[19]};
    const float* edge_W[3]   = {(const float*)d_in[8],  (const float*)d_in[14], (const float*)d_in[20]};
    const float* att_edge[3] = {(const float*)d_in[9],  (const float*)d_in[15], (const float*)d_in[21]};
    const float* bias[3]     = {(const float*)d_in[10], (const float*)d_in[16], (const float*)d_in[22]};
    const float* fc1_W = (const float*)d_in[23];
    const float* fc1_b = (const float*)d_in[24];
    const float* fc2_W = (const float*)d_in[25];
    const float* fc2_b = (const float*)d_in[26];
    float* out = (float*)d_out;

    char* p = (char*)d_ws;
    auto alloc = [&](size_t bytes) -> void* {
        void* r = (void*)p;
        p += (bytes + 255) & ~(size_t)255;
        return r;
    };
    int*   deg      = (int*)alloc((size_t)NN * 4);
    float* loop_sum = (float*)alloc((size_t)NN * 8);
    int*   part     = (int*)alloc((size_t)NCHUNK * 4);
    int*   row      = (int*)alloc((size_t)(NN + 1) * 4);
    int*   cursor   = (int*)alloc((size_t)NN * 4);
    int*   csr_src  = (int*)alloc((size_t)ETOT * 4);
    float* csr_ea   = (float*)alloc((size_t)ETOT * 8);
    float* a_srcB   = (float*)alloc((size_t)NN * 4 * 4);
    float* a_dstB   = (float*)alloc((size_t)NN * 4 * 4);
    float* coef     = (float*)alloc(256);
    float* mdenM    = (float*)alloc((size_t)NN * 4 * 4);
    float* mdenD    = (float*)alloc((size_t)NN * 4 * 4);
    float* xw       = (float*)alloc((size_t)NN * 256 * 4);
    float* hA       = (float*)alloc((size_t)NN * DH * 4);
    float* hB       = (float*)alloc((size_t)NN * DH * 4);

    const int BT = 256;
    const int nodeBlocks  = (NN + BT - 1) / BT;
    const int edgeBlocks  = (NE + BT - 1) / BT;
    const int chunkBlocks = (NCHUNK + BT - 1) / BT;
    const int ndBlocks    = (NN * DH + BT - 1) / BT;
    const int nodeWaveBlocks = (NN * 64 + BT - 1) / BT;

    k_zero_init<<<nodeBlocks, BT, 0, stream>>>(deg, loop_sum);
    k_deg_loopsum<<<edgeBlocks, BT, 0, stream>>>(ei, ea, deg, loop_sum);
    k_scan_a<<<chunkBlocks, BT, 0, stream>>>(deg, part);
    k_scan_b<<<1, 64, 0, stream>>>(part);
    k_scan_c<<<chunkBlocks, BT, 0, stream>>>(deg, part, row, cursor);
    k_fill_csr<<<edgeBlocks, BT, 0, stream>>>(ei, ea, cursor, csr_src, csr_ea);
    k_fill_self<<<nodeBlocks, BT, 0, stream>>>(deg, row, loop_sum, csr_src, csr_ea);
    k_encoder<<<ndBlocks, BT, 0, stream>>>(x, enc_W, enc_b, hA);

    float* hin = hA;
    float* hout = hB;

    for (int L = 0; L < 3; L++) {
        if (L < 2) {
            constexpr int H = 4;
            constexpr int C = H * DH;
            k_xw_v4<C><<<((NN / 4) * (C / 8) + BT - 1) / BT, BT, 0, stream>>>(hin, lin_W[L], xw);
            k_att_s<H><<<(NN * H + BT - 1) / BT, BT, 0, stream>>>(xw, att_src[L], att_dst[L], a_srcB, a_dstB);
            k_coef_s<H><<<1, 64, 0, stream>>>(edge_W[L], att_edge[L], coef);
            k_mden<H><<<nodeBlocks, BT, 0, stream>>>(row, csr_src, csr_ea, a_srcB, a_dstB, coef, mdenM, mdenD);
            k_agg<H><<<nodeWaveBlocks, BT, 0, stream>>>(row, csr_src, csr_ea, a_srcB, a_dstB, coef,
                                                       mdenM, mdenD, xw, bias[L], hin, hout);
        } else {
            constexpr int H = 1;
            constexpr int C = H * DH;
            k_xw_v4<C><<<((NN / 4) * (C / 8) + BT - 1) / BT, BT, 0, stream>>>(hin, lin_W[L], xw);
            k_att_s<H><<<(NN * H + BT - 1) / BT, BT, 0, stream>>>(xw, att_src[L], att_dst[L], a_srcB, a_dstB);
            k_coef_s<H><<<1, 64, 0, stream>>>(edge_W[L], att_edge[L], coef);
            k_mden<H><<<nodeBlocks, BT, 0, stream>>>(row, csr_src, csr_ea, a_srcB, a_dstB, coef, mdenM, mdenD);
            k_agg<H><<<nodeWaveBlocks, BT, 0, stream>>>(row, csr_src, csr_ea, a_srcB, a_dstB, coef,
                                                       mdenM, mdenD, xw, bias[L], hin, hout);
        }
        float* t = hin; hin = hout; hout = t;
    }
    k_head_s<<<nodeBlocks, BT, 0, stream>>>(hin, fc1_W, fc1_b, fc2_W, fc2_b, out);
}

// Round 8
// 1087.170 us; speedup vs baseline: 2.6033x; 1.0951x over previous
//
#include <hip/hip_runtime.h>
#include <math.h>

#define NN 100000
#define NE 1000000
#define DH 64
constexpr int ETOT = NE + NN;
constexpr int CHUNK = 100;
constexpr int NCHUNK = (NN + CHUNK - 1) / CHUNK;   // 1000

typedef _Float16 half_t;

// ---------------- degree + self-loop attr sums ----------------

__global__ void k_zero_init(int* __restrict__ deg, float* __restrict__ loop_sum) {
    int i = blockIdx.x * blockDim.x + threadIdx.x;
    if (i < NN) {
        deg[i] = 0;
        loop_sum[2 * i] = 0.f;
        loop_sum[2 * i + 1] = 0.f;
    }
}

__global__ void k_deg_loopsum(const int* __restrict__ ei, const float* __restrict__ ea,
                              int* __restrict__ deg, float* __restrict__ loop_sum) {
    int e = blockIdx.x * blockDim.x + threadIdx.x;
    if (e < NE) {
        int d = ei[NE + e];
        atomicAdd(&deg[d], 1);
        atomicAdd(&loop_sum[2 * d], ea[2 * e]);
        atomicAdd(&loop_sum[2 * d + 1], ea[2 * e + 1]);
    }
}

// ---------------- chunked prefix scan (scalar) ----------------

__global__ void k_scan_a(const int* __restrict__ deg, int* __restrict__ part) {
    int c = blockIdx.x * blockDim.x + threadIdx.x;
    if (c >= NCHUNK) return;
    int lo = c * CHUNK;
    int hi = lo + CHUNK; if (hi > NN) hi = NN;
    int s = 0;
    for (int i = lo; i < hi; i++) s += deg[i];
    part[c] = s;
}

__global__ void k_scan_b(int* __restrict__ part) {
    if (threadIdx.x || blockIdx.x) return;
    int run = 0;
    for (int i = 0; i < NCHUNK; i++) { int t = part[i]; part[i] = run; run += t; }
}

__global__ void k_scan_c(const int* __restrict__ deg, const int* __restrict__ part,
                         int* __restrict__ row, int* __restrict__ cursor) {
    int c = blockIdx.x * blockDim.x + threadIdx.x;
    if (c >= NCHUNK) return;
    int lo = c * CHUNK;
    int hi = lo + CHUNK; if (hi > NN) hi = NN;
    int run = part[c];
    for (int i = lo; i < hi; i++) {
        int r = run + i;
        row[i] = r;
        cursor[i] = r;
        run += deg[i];
    }
    if (c == NCHUNK - 1) row[NN] = run + NN;
}

__global__ void k_fill_csr(const int* __restrict__ ei, const float* __restrict__ ea,
                           int* __restrict__ cursor, int* __restrict__ csr_src,
                           float* __restrict__ csr_ea) {
    int e = blockIdx.x * blockDim.x + threadIdx.x;
    if (e < NE) {
        int s = ei[e];
        int d = ei[NE + e];
        int pos = atomicAdd(&cursor[d], 1);
        csr_src[pos] = s;
        csr_ea[2 * pos] = ea[2 * e];
        csr_ea[2 * pos + 1] = ea[2 * e + 1];
    }
}

__global__ void k_fill_self(const int* __restrict__ deg, const int* __restrict__ row,
                            const float* __restrict__ loop_sum,
                            int* __restrict__ csr_src, float* __restrict__ csr_ea) {
    int n = blockIdx.x * blockDim.x + threadIdx.x;
    if (n < NN) {
        int pos = row[n] + deg[n];
        csr_src[pos] = n;
        float dv = fmaxf((float)deg[n], 1.0f);
        csr_ea[2 * pos] = loop_sum[2 * n] / dv;
        csr_ea[2 * pos + 1] = loop_sum[2 * n + 1] / dv;
    }
}

// ---------------- encoder ----------------

__global__ void k_encoder(const float* __restrict__ x, const float* __restrict__ W,
                          const float* __restrict__ b, float* __restrict__ h) {
    int idx = blockIdx.x * blockDim.x + threadIdx.x;
    int n = idx >> 6, d = idx & 63;
    if (n < NN) {
        float v = x[2 * n] * W[d] + x[2 * n + 1] * W[DH + d] + b[d];
        h[idx] = fmaxf(v, 0.f);
    }
}

// ---------------- xw = h @ lin_W, register-blocked, fp16 output ----------------

template <int C>
__global__ void k_xw_v4(const float* __restrict__ h, const float* __restrict__ W,
                        half_t* __restrict__ xw) {
    constexpr int TPN = C / 8;
    int gid = blockIdx.x * blockDim.x + threadIdx.x;
    int nb = gid / TPN;
    int c0 = (gid % TPN) * 8;
    if (nb >= NN / 4) return;
    int n0 = nb * 4;
    const float* hrow = h + (size_t)n0 * DH;
    const float* wp = W + c0;
    float acc[4][8];
#pragma unroll
    for (int i = 0; i < 4; i++)
#pragma unroll
        for (int j = 0; j < 8; j++) acc[i][j] = 0.f;
    for (int q = 0; q < DH / 4; q++) {
        float hreg[4][4];
#pragma unroll
        for (int i = 0; i < 4; i++) {
            float4 v = *(const float4*)(hrow + i * DH + q * 4);
            hreg[i][0] = v.x; hreg[i][1] = v.y; hreg[i][2] = v.z; hreg[i][3] = v.w;
        }
#pragma unroll
        for (int t = 0; t < 4; t++) {
            int k = q * 4 + t;
            const float4* w4 = (const float4*)(wp + (size_t)k * C);
            float4 a = w4[0], b = w4[1];
            float wv[8] = {a.x, a.y, a.z, a.w, b.x, b.y, b.z, b.w};
#pragma unroll
            for (int i = 0; i < 4; i++) {
                float hk = hreg[i][t];
#pragma unroll
                for (int j = 0; j < 8; j++) acc[i][j] += hk * wv[j];
            }
        }
    }
#pragma unroll
    for (int i = 0; i < 4; i++) {
        half_t hv[8];
#pragma unroll
        for (int j = 0; j < 8; j++) hv[j] = (half_t)acc[i][j];
        *(float4*)(xw + (size_t)(n0 + i) * C + c0) = *(float4*)hv;   // 8 halves = 16B
    }
}

// ---------------- a_src/a_dst from fp16 xw ----------------

template <int H>
__global__ void k_att_s(const half_t* __restrict__ xw, const float* __restrict__ att_src,
                        const float* __restrict__ att_dst,
                        float* __restrict__ a_src, float* __restrict__ a_dst) {
    int idx = blockIdx.x * blockDim.x + threadIdx.x;
    int n = idx / H, hh = idx % H;
    if (n >= NN) return;
    const float4* xv4 = (const float4*)(xw + (size_t)n * (H * DH) + hh * DH);
    float ps = 0.f, pd = 0.f;
    for (int q = 0; q < DH / 8; q++) {
        float4 raw = xv4[q];
        const half_t* hp = (const half_t*)&raw;
        const float4* as4 = (const float4*)(att_src + hh * DH + q * 8);
        const float4* ad4 = (const float4*)(att_dst + hh * DH + q * 8);
        float4 a0 = as4[0], a1 = as4[1], d0 = ad4[0], d1 = ad4[1];
        float xs[8];
#pragma unroll
        for (int k = 0; k < 8; k++) xs[k] = (float)hp[k];
        ps += xs[0] * a0.x + xs[1] * a0.y + xs[2] * a0.z + xs[3] * a0.w
            + xs[4] * a1.x + xs[5] * a1.y + xs[6] * a1.z + xs[7] * a1.w;
        pd += xs[0] * d0.x + xs[1] * d0.y + xs[2] * d0.z + xs[3] * d0.w
            + xs[4] * d1.x + xs[5] * d1.y + xs[6] * d1.z + xs[7] * d1.w;
    }
    a_src[idx] = ps;
    a_dst[idx] = pd;
}

// ---------------- edge coef ----------------

template <int H>
__global__ void k_coef_s(const float* __restrict__ edge_W, const float* __restrict__ att_edge,
                         float* __restrict__ coef) {
    if (blockIdx.x || threadIdx.x) return;
    for (int w = 0; w < 2; w++)
        for (int h = 0; h < H; h++) {
            float s = 0.f;
            for (int d = 0; d < DH; d++)
                s += edge_W[w * H * DH + h * DH + d] * att_edge[h * DH + d];
            coef[w * H + h] = s;
        }
}

// ---------------- per-node m, den + per-edge ex: one THREAD per node ----------------

template <int H>
__device__ inline float logit_of(const float* __restrict__ a_src, const float* ad,
                                 const float* cf, int s, float e0, float e1, int h) {
    float lg = a_src[s * H + h] + ad[h] + e0 * cf[h] + e1 * cf[H + h];
    return (lg > 0.f) ? lg : 0.2f * lg;
}

template <int H>
__global__ void k_mden(const int* __restrict__ row, const int* __restrict__ csr_src,
                       const float* __restrict__ csr_ea, const float* __restrict__ a_src,
                       const float* __restrict__ a_dst, const float* __restrict__ coef,
                       float* __restrict__ exbuf, float* __restrict__ denout) {
    int n = blockIdx.x * blockDim.x + threadIdx.x;
    if (n >= NN) return;
    int r0 = row[n], r1 = row[n + 1];
    float ad[H], cf[2 * H], m[H], den[H];
#pragma unroll
    for (int h = 0; h < H; h++) { ad[h] = a_dst[n * H + h]; m[h] = -1e30f; den[h] = 0.f; }
#pragma unroll
    for (int i = 0; i < 2 * H; i++) cf[i] = coef[i];
    for (int j = r0; j < r1; j++) {
        int s = csr_src[j];
        float e0 = csr_ea[2 * j], e1 = csr_ea[2 * j + 1];
#pragma unroll
        for (int h = 0; h < H; h++) {
            float lg = logit_of<H>(a_src, ad, cf, s, e0, e1, h);
            m[h] = fmaxf(m[h], lg);
        }
    }
    for (int j = r0; j < r1; j++) {
        int s = csr_src[j];
        float e0 = csr_ea[2 * j], e1 = csr_ea[2 * j + 1];
#pragma unroll
        for (int h = 0; h < H; h++) {
            float lg = logit_of<H>(a_src, ad, cf, s, e0, e1, h);
            float ex = __expf(lg - m[h]);
            den[h] += ex;
            exbuf[(size_t)j * H + h] = ex;
        }
    }
#pragma unroll
    for (int h = 0; h < H; h++) denout[n * H + h] = den[h];
}

// ---------------- aggregate: one WAVE per node, lane = dim, pure gather-FMA ----------------

template <int H>
__global__ void k_agg(const int* __restrict__ row, const int* __restrict__ csr_src,
                      const float* __restrict__ exbuf, const float* __restrict__ mden_d,
                      const half_t* __restrict__ xw, const float* __restrict__ bias,
                      const float* __restrict__ hin, float* __restrict__ hout) {
    int gid = blockIdx.x * blockDim.x + threadIdx.x;
    int n = gid >> 6;
    int lane = gid & 63;
    if (n >= NN) return;
    int r0 = row[n], r1 = row[n + 1];
    float inv[H], acc[H];
#pragma unroll
    for (int h = 0; h < H; h++) {
        inv[h] = 1.f / (mden_d[n * H + h] + 1e-16f);
        acc[h] = 0.f;
    }
    for (int j = r0; j < r1; j++) {
        int s = csr_src[j];                           // wave-uniform
        const half_t* xp = xw + (size_t)s * (H * DH) + lane;
        float exv[H];
        if constexpr (H == 4) {
            float4 e4 = *(const float4*)(exbuf + (size_t)j * 4);   // uniform 16B
            exv[0] = e4.x; exv[1] = e4.y; exv[2] = e4.z; exv[3] = e4.w;
        } else {
            exv[0] = exbuf[j];
        }
#pragma unroll
        for (int h = 0; h < H; h++)
            acc[h] += exv[h] * (float)xp[h * DH];     // 128B coalesced fp16 gather
    }
    float val = 0.f;
#pragma unroll
    for (int h = 0; h < H; h++) val += acc[h] * inv[h];
    val *= (1.0f / H);
    val += bias[lane];
    val = fmaxf(val, 0.f);
    hout[n * DH + lane] = val + hin[n * DH + lane];
}

// ---------------- final MLP head ----------------

__global__ void k_head_s(const float* __restrict__ h, const float* __restrict__ fc1_W,
                         const float* __restrict__ fc1_b, const float* __restrict__ fc2_W,
                         const float* __restrict__ fc2_b, float* __restrict__ out) {
    int n = blockIdx.x * blockDim.x + threadIdx.x;
    if (n >= NN) return;
    float y[32];
#pragma unroll
    for (int c = 0; c < 32; c++) y[c] = fc1_b[c];
    for (int k = 0; k < DH; k++) {
        float hk = h[n * DH + k];
#pragma unroll
        for (int c = 0; c < 32; c++) y[c] += hk * fc1_W[k * 32 + c];
    }
    float o0 = fc2_b[0], o1 = fc2_b[1];
#pragma unroll
    for (int c = 0; c < 32; c++) {
        float yr = fmaxf(y[c], 0.f);
        o0 += yr * fc2_W[c * 2];
        o1 += yr * fc2_W[c * 2 + 1];
    }
    out[2 * n] = tanhf(o0);
    out[2 * n + 1] = tanhf(o1);
}

// ---------------- launch ----------------

extern "C" void kernel_launch(void* const* d_in, const int* in_sizes, int n_in,
                              void* d_out, int out_size, void* d_ws, size_t ws_size,
                              hipStream_t stream) {
    const float* x     = (const float*)d_in[0];
    const int*   ei    = (const int*)d_in[1];
    const float* ea    = (const float*)d_in[2];
    const float* enc_W = (const float*)d_in[3];
    const float* enc_b = (const float*)d_in[4];
    const float* lin_W[3]    = {(const float*)d_in[5],  (const float*)d_in[11], (const float*)d_in[17]};
    const float* att_src[3]  = {(const float*)d_in[6],  (const float*)d_in[12], (const float*)d_in[18]};
    const float* att_dst[3]  = {(const float*)d_in[7],  (const float*)d_in[13], (const float*)d_in[19]};
    const float* edge_W[3]   = {(const float*)d_in[8],  (const float*)d_in[14], (const float*)d_in[20]};
    const float* att_edge[3] = {(const float*)d_in[9],  (const float*)d_in[15], (const float*)d_in[21]};
    const float* bias[3]     = {(const float*)d_in[10], (const float*)d_in[16], (const float*)d_in[22]};
    const float* fc1_W = (const float*)d_in[23];
    const float* fc1_b = (const float*)d_in[24];
    const float* fc2_W = (const float*)d_in[25];
    const float* fc2_b = (const float*)d_in[26];
    float* out = (float*)d_out;

    char* p = (char*)d_ws;
    auto alloc = [&](size_t bytes) -> void* {
        void* r = (void*)p;
        p += (bytes + 255) & ~(size_t)255;
        return r;
    };
    int*    deg      = (int*)alloc((size_t)NN * 4);
    float*  loop_sum = (float*)alloc((size_t)NN * 8);
    int*    part     = (int*)alloc((size_t)NCHUNK * 4);
    int*    row      = (int*)alloc((size_t)(NN + 1) * 4);
    int*    cursor   = (int*)alloc((size_t)NN * 4);
    int*    csr_src  = (int*)alloc((size_t)ETOT * 4);
    float*  csr_ea   = (float*)alloc((size_t)ETOT * 8);
    float*  a_srcB   = (float*)alloc((size_t)NN * 4 * 4);
    float*  a_dstB   = (float*)alloc((size_t)NN * 4 * 4);
    float*  coef     = (float*)alloc(256);
    float*  exbuf    = (float*)alloc((size_t)ETOT * 4 * 4);
    float*  mdenD    = (float*)alloc((size_t)NN * 4 * 4);
    half_t* xw       = (half_t*)alloc((size_t)NN * 256 * 2);
    float*  hA       = (float*)alloc((size_t)NN * DH * 4);
    float*  hB       = (float*)alloc((size_t)NN * DH * 4);

    const int BT = 256;
    const int nodeBlocks  = (NN + BT - 1) / BT;
    const int edgeBlocks  = (NE + BT - 1) / BT;
    const int chunkBlocks = (NCHUNK + BT - 1) / BT;
    const int ndBlocks    = (NN * DH + BT - 1) / BT;
    const int nodeWaveBlocks = (NN * 64 + BT - 1) / BT;

    k_zero_init<<<nodeBlocks, BT, 0, stream>>>(deg, loop_sum);
    k_deg_loopsum<<<edgeBlocks, BT, 0, stream>>>(ei, ea, deg, loop_sum);
    k_scan_a<<<chunkBlocks, BT, 0, stream>>>(deg, part);
    k_scan_b<<<1, 64, 0, stream>>>(part);
    k_scan_c<<<chunkBlocks, BT, 0, stream>>>(deg, part, row, cursor);
    k_fill_csr<<<edgeBlocks, BT, 0, stream>>>(ei, ea, cursor, csr_src, csr_ea);
    k_fill_self<<<nodeBlocks, BT, 0, stream>>>(deg, row, loop_sum, csr_src, csr_ea);
    k_encoder<<<ndBlocks, BT, 0, stream>>>(x, enc_W, enc_b, hA);

    float* hin = hA;
    float* hout = hB;

    for (int L = 0; L < 3; L++) {
        if (L < 2) {
            constexpr int H = 4;
            constexpr int C = H * DH;
            k_xw_v4<C><<<((NN / 4) * (C / 8) + BT - 1) / BT, BT, 0, stream>>>(hin, lin_W[L], xw);
            k_att_s<H><<<(NN * H + BT - 1) / BT, BT, 0, stream>>>(xw, att_src[L], att_dst[L], a_srcB, a_dstB);
            k_coef_s<H><<<1, 64, 0, stream>>>(edge_W[L], att_edge[L], coef);
            k_mden<H><<<nodeBlocks, BT, 0, stream>>>(row, csr_src, csr_ea, a_srcB, a_dstB, coef, exbuf, mdenD);
            k_agg<H><<<nodeWaveBlocks, BT, 0, stream>>>(row, csr_src, exbuf, mdenD, xw, bias[L], hin, hout);
        } else {
            constexpr int H = 1;
            constexpr int C = H * DH;
            k_xw_v4<C><<<((NN / 4) * (C / 8) + BT - 1) / BT, BT, 0, stream>>>(hin, lin_W[L], xw);
            k_att_s<H><<<(NN * H + BT - 1) / BT, BT, 0, stream>>>(xw, att_src[L], att_dst[L], a_srcB, a_dstB);
            k_coef_s<H><<<1, 64, 0, stream>>>(edge_W[L], att_edge[L], coef);
            k_mden<H><<<nodeBlocks, BT, 0, stream>>>(row, csr_src, csr_ea, a_srcB, a_dstB, coef, exbuf, mdenD);
            k_agg<H><<<nodeWaveBlocks, BT, 0, stream>>>(row, csr_src, exbuf, mdenD, xw, bias[L], hin, hout);
        }
        float* t = hin; hin = hout; hout = t;
    }
    k_head_s<<<nodeBlocks, BT, 0, stream>>>(hin, fc1_W, fc1_b, fc2_W, fc2_b, out);
}

// Round 9
// 969.411 us; speedup vs baseline: 2.9196x; 1.1215x over previous
//
#include <hip/hip_runtime.h>
#include <math.h>

#define NN 100000
#define NE 1000000
#define DH 64
constexpr int ETOT = NE + NN;
constexpr int CHUNK = 100;
constexpr int NCHUNK = (NN + CHUNK - 1) / CHUNK;   // 1000

typedef _Float16 half_t;

// AoS edge record: {int src; float e0; float e1; int pad} stored as int4

// ---------------- degree ----------------

__global__ void k_zero_init(int* __restrict__ deg) {
    int i = blockIdx.x * blockDim.x + threadIdx.x;
    if (i < NN) deg[i] = 0;
}

__global__ void k_deg(const int* __restrict__ ei, int* __restrict__ deg) {
    int e = blockIdx.x * blockDim.x + threadIdx.x;
    if (e < NE) atomicAdd(&deg[ei[NE + e]], 1);
}

// ---------------- chunked prefix scan (scalar) ----------------

__global__ void k_scan_a(const int* __restrict__ deg, int* __restrict__ part) {
    int c = blockIdx.x * blockDim.x + threadIdx.x;
    if (c >= NCHUNK) return;
    int lo = c * CHUNK;
    int hi = lo + CHUNK; if (hi > NN) hi = NN;
    int s = 0;
    for (int i = lo; i < hi; i++) s += deg[i];
    part[c] = s;
}

__global__ void k_scan_b(int* __restrict__ part) {
    if (threadIdx.x || blockIdx.x) return;
    int run = 0;
    for (int i = 0; i < NCHUNK; i++) { int t = part[i]; part[i] = run; run += t; }
}

__global__ void k_scan_c(const int* __restrict__ deg, const int* __restrict__ part,
                         int* __restrict__ row, int* __restrict__ cursor) {
    int c = blockIdx.x * blockDim.x + threadIdx.x;
    if (c >= NCHUNK) return;
    int lo = c * CHUNK;
    int hi = lo + CHUNK; if (hi > NN) hi = NN;
    int run = part[c];
    for (int i = lo; i < hi; i++) {
        int r = run + i;
        row[i] = r;
        cursor[i] = r;
        run += deg[i];
    }
    if (c == NCHUNK - 1) row[NN] = run + NN;
}

__global__ void k_fill_csr(const int* __restrict__ ei, const float* __restrict__ ea,
                           int* __restrict__ cursor, int4* __restrict__ csr) {
    int e = blockIdx.x * blockDim.x + threadIdx.x;
    if (e < NE) {
        int s = ei[e];
        int d = ei[NE + e];
        int pos = atomicAdd(&cursor[d], 1);
        int4 rec;
        rec.x = s;
        rec.y = __float_as_int(ea[2 * e]);
        rec.z = __float_as_int(ea[2 * e + 1]);
        rec.w = 0;
        csr[pos] = rec;
    }
}

// self-loop record: mean of the node's own (already-filled) segment
__global__ void k_fill_self(const int* __restrict__ deg, const int* __restrict__ row,
                            int4* __restrict__ csr) {
    int n = blockIdx.x * blockDim.x + threadIdx.x;
    if (n >= NN) return;
    int r0 = row[n];
    int dg = deg[n];
    float s0 = 0.f, s1 = 0.f;
    for (int j = r0; j < r0 + dg; j++) {
        int4 rec = csr[j];
        s0 += __int_as_float(rec.y);
        s1 += __int_as_float(rec.z);
    }
    float dv = fmaxf((float)dg, 1.0f);
    int4 self;
    self.x = n;
    self.y = __float_as_int(s0 / dv);
    self.z = __float_as_int(s1 / dv);
    self.w = 0;
    csr[r0 + dg] = self;
}

// ---------------- encoder ----------------

__global__ void k_encoder(const float* __restrict__ x, const float* __restrict__ W,
                          const float* __restrict__ b, float* __restrict__ h) {
    int idx = blockIdx.x * blockDim.x + threadIdx.x;
    int n = idx >> 6, d = idx & 63;
    if (n < NN) {
        float v = x[2 * n] * W[d] + x[2 * n + 1] * W[DH + d] + b[d];
        h[idx] = fmaxf(v, 0.f);
    }
}

// ---------------- xw = h @ lin_W, register-blocked, fp16 output ----------------

template <int C>
__global__ void k_xw_v4(const float* __restrict__ h, const float* __restrict__ W,
                        half_t* __restrict__ xw) {
    constexpr int TPN = C / 8;
    int gid = blockIdx.x * blockDim.x + threadIdx.x;
    int nb = gid / TPN;
    int c0 = (gid % TPN) * 8;
    if (nb >= NN / 4) return;
    int n0 = nb * 4;
    const float* hrow = h + (size_t)n0 * DH;
    const float* wp = W + c0;
    float acc[4][8];
#pragma unroll
    for (int i = 0; i < 4; i++)
#pragma unroll
        for (int j = 0; j < 8; j++) acc[i][j] = 0.f;
    for (int q = 0; q < DH / 4; q++) {
        float hreg[4][4];
#pragma unroll
        for (int i = 0; i < 4; i++) {
            float4 v = *(const float4*)(hrow + i * DH + q * 4);
            hreg[i][0] = v.x; hreg[i][1] = v.y; hreg[i][2] = v.z; hreg[i][3] = v.w;
        }
#pragma unroll
        for (int t = 0; t < 4; t++) {
            int k = q * 4 + t;
            const float4* w4 = (const float4*)(wp + (size_t)k * C);
            float4 a = w4[0], b = w4[1];
            float wv[8] = {a.x, a.y, a.z, a.w, b.x, b.y, b.z, b.w};
#pragma unroll
            for (int i = 0; i < 4; i++) {
                float hk = hreg[i][t];
#pragma unroll
                for (int j = 0; j < 8; j++) acc[i][j] += hk * wv[j];
            }
        }
    }
#pragma unroll
    for (int i = 0; i < 4; i++) {
        half_t hv[8];
#pragma unroll
        for (int j = 0; j < 8; j++) hv[j] = (half_t)acc[i][j];
        *(float4*)(xw + (size_t)(n0 + i) * C + c0) = *(float4*)hv;
    }
}

// ---------------- a_src/a_dst from fp16 xw ----------------

template <int H>
__global__ void k_att_s(const half_t* __restrict__ xw, const float* __restrict__ att_src,
                        const float* __restrict__ att_dst,
                        float* __restrict__ a_src, float* __restrict__ a_dst) {
    int idx = blockIdx.x * blockDim.x + threadIdx.x;
    int n = idx / H, hh = idx % H;
    if (n >= NN) return;
    const float4* xv4 = (const float4*)(xw + (size_t)n * (H * DH) + hh * DH);
    float ps = 0.f, pd = 0.f;
    for (int q = 0; q < DH / 8; q++) {
        float4 raw = xv4[q];
        const half_t* hp = (const half_t*)&raw;
        const float4* as4 = (const float4*)(att_src + hh * DH + q * 8);
        const float4* ad4 = (const float4*)(att_dst + hh * DH + q * 8);
        float4 a0 = as4[0], a1 = as4[1], d0 = ad4[0], d1 = ad4[1];
        float xs[8];
#pragma unroll
        for (int k = 0; k < 8; k++) xs[k] = (float)hp[k];
        ps += xs[0] * a0.x + xs[1] * a0.y + xs[2] * a0.z + xs[3] * a0.w
            + xs[4] * a1.x + xs[5] * a1.y + xs[6] * a1.z + xs[7] * a1.w;
        pd += xs[0] * d0.x + xs[1] * d0.y + xs[2] * d0.z + xs[3] * d0.w
            + xs[4] * d1.x + xs[5] * d1.y + xs[6] * d1.z + xs[7] * d1.w;
    }
    a_src[idx] = ps;
    a_dst[idx] = pd;
}

// ---------------- edge coef ----------------

template <int H>
__global__ void k_coef_s(const float* __restrict__ edge_W, const float* __restrict__ att_edge,
                         float* __restrict__ coef) {
    if (blockIdx.x || threadIdx.x) return;
    for (int w = 0; w < 2; w++)
        for (int h = 0; h < H; h++) {
            float s = 0.f;
            for (int d = 0; d < DH; d++)
                s += edge_W[w * H * DH + h * DH + d] * att_edge[h * DH + d];
            coef[w * H + h] = s;
        }
}

// ---------------- per-node den + per-edge ex: single pass, no max-sub ----------------
// exp(lg)/sum(exp(lg)) == exp(lg-m)/sum(exp(lg-m)); logits are O(+-10), safe in f32.

template <int H>
__global__ void k_mden(const int* __restrict__ row, const int4* __restrict__ csr,
                       const float* __restrict__ a_src, const float* __restrict__ a_dst,
                       const float* __restrict__ coef,
                       float* __restrict__ exbuf, float* __restrict__ denout) {
    int n = blockIdx.x * blockDim.x + threadIdx.x;
    if (n >= NN) return;
    int r0 = row[n], r1 = row[n + 1];
    float ad[H], cf[2 * H], den[H];
#pragma unroll
    for (int h = 0; h < H; h++) { ad[h] = a_dst[n * H + h]; den[h] = 0.f; }
#pragma unroll
    for (int i = 0; i < 2 * H; i++) cf[i] = coef[i];
    for (int j = r0; j < r1; j++) {
        int4 rec = csr[j];
        int s = rec.x;
        float e0 = __int_as_float(rec.y), e1 = __int_as_float(rec.z);
#pragma unroll
        for (int h = 0; h < H; h++) {
            float lg = a_src[s * H + h] + ad[h] + e0 * cf[h] + e1 * cf[H + h];
            lg = (lg > 0.f) ? lg : 0.2f * lg;
            float ex = __expf(lg);
            den[h] += ex;
            exbuf[(size_t)j * H + h] = ex;
        }
    }
#pragma unroll
    for (int h = 0; h < H; h++) denout[n * H + h] = den[h];
}

// ---------------- aggregate: one WAVE per node, lane = dim, pure gather-FMA ----------------

template <int H>
__global__ void k_agg(const int* __restrict__ row, const int4* __restrict__ csr,
                      const float* __restrict__ exbuf, const float* __restrict__ mden_d,
                      const half_t* __restrict__ xw, const float* __restrict__ bias,
                      const float* __restrict__ hin, float* __restrict__ hout) {
    int gid = blockIdx.x * blockDim.x + threadIdx.x;
    int n = gid >> 6;
    int lane = gid & 63;
    if (n >= NN) return;
    int r0 = row[n], r1 = row[n + 1];
    float inv[H], acc[H];
#pragma unroll
    for (int h = 0; h < H; h++) {
        inv[h] = 1.f / (mden_d[n * H + h] + 1e-16f);
        acc[h] = 0.f;
    }
    for (int j = r0; j < r1; j++) {
        int s = csr[j].x;                             // wave-uniform
        const half_t* xp = xw + (size_t)s * (H * DH) + lane;
        float exv[H];
        if constexpr (H == 4) {
            float4 e4 = *(const float4*)(exbuf + (size_t)j * 4);
            exv[0] = e4.x; exv[1] = e4.y; exv[2] = e4.z; exv[3] = e4.w;
        } else {
            exv[0] = exbuf[j];
        }
#pragma unroll
        for (int h = 0; h < H; h++)
            acc[h] += exv[h] * (float)xp[h * DH];     // 128B coalesced fp16 gather
    }
    float val = 0.f;
#pragma unroll
    for (int h = 0; h < H; h++) val += acc[h] * inv[h];
    val *= (1.0f / H);
    val += bias[lane];
    val = fmaxf(val, 0.f);
    hout[n * DH + lane] = val + hin[n * DH + lane];
}

// ---------------- final MLP head ----------------

__global__ void k_head_s(const float* __restrict__ h, const float* __restrict__ fc1_W,
                         const float* __restrict__ fc1_b, const float* __restrict__ fc2_W,
                         const float* __restrict__ fc2_b, float* __restrict__ out) {
    int n = blockIdx.x * blockDim.x + threadIdx.x;
    if (n >= NN) return;
    float y[32];
#pragma unroll
    for (int c = 0; c < 32; c++) y[c] = fc1_b[c];
    for (int k = 0; k < DH; k++) {
        float hk = h[n * DH + k];
#pragma unroll
        for (int c = 0; c < 32; c++) y[c] += hk * fc1_W[k * 32 + c];
    }
    float o0 = fc2_b[0], o1 = fc2_b[1];
#pragma unroll
    for (int c = 0; c < 32; c++) {
        float yr = fmaxf(y[c], 0.f);
        o0 += yr * fc2_W[c * 2];
        o1 += yr * fc2_W[c * 2 + 1];
    }
    out[2 * n] = tanhf(o0);
    out[2 * n + 1] = tanhf(o1);
}

// ---------------- launch ----------------

extern "C" void kernel_launch(void* const* d_in, const int* in_sizes, int n_in,
                              void* d_out, int out_size, void* d_ws, size_t ws_size,
                              hipStream_t stream) {
    const float* x     = (const float*)d_in[0];
    const int*   ei    = (const int*)d_in[1];
    const float* ea    = (const float*)d_in[2];
    const float* enc_W = (const float*)d_in[3];
    const float* enc_b = (const float*)d_in[4];
    const float* lin_W[3]    = {(const float*)d_in[5],  (const float*)d_in[11], (const float*)d_in[17]};
    const float* att_src[3]  = {(const float*)d_in[6],  (const float*)d_in[12], (const float*)d_in[18]};
    const float* att_dst[3]  = {(const float*)d_in[7],  (const float*)d_in[13], (const float*)d_in[19]};
    const float* edge_W[3]   = {(const float*)d_in[8],  (const float*)d_in[14], (const float*)d_in[20]};
    const float* att_edge[3] = {(const float*)d_in[9],  (const float*)d_in[15], (const float*)d_in[21]};
    const float* bias[3]     = {(const float*)d_in[10], (const float*)d_in[16], (const float*)d_in[22]};
    const float* fc1_W = (const float*)d_in[23];
    const float* fc1_b = (const float*)d_in[24];
    const float* fc2_W = (const float*)d_in[25];
    const float* fc2_b = (const float*)d_in[26];
    float* out = (float*)d_out;

    char* p = (char*)d_ws;
    auto alloc = [&](size_t bytes) -> void* {
        void* r = (void*)p;
        p += (bytes + 255) & ~(size_t)255;
        return r;
    };
    int*    deg    = (int*)alloc((size_t)NN * 4);
    int*    part   = (int*)alloc((size_t)NCHUNK * 4);
    int*    row    = (int*)alloc((size_t)(NN + 1) * 4);
    int*    cursor = (int*)alloc((size_t)NN * 4);
    int4*   csr    = (int4*)alloc((size_t)ETOT * 16);
    float*  a_srcB = (float*)alloc((size_t)NN * 4 * 4);
    float*  a_dstB = (float*)alloc((size_t)NN * 4 * 4);
    float*  coef   = (float*)alloc(256);
    float*  exbuf  = (float*)alloc((size_t)ETOT * 4 * 4);
    float*  mdenD  = (float*)alloc((size_t)NN * 4 * 4);
    half_t* xw     = (half_t*)alloc((size_t)NN * 256 * 2);
    float*  hA     = (float*)alloc((size_t)NN * DH * 4);
    float*  hB     = (float*)alloc((size_t)NN * DH * 4);

    const int BT = 256;
    const int nodeBlocks  = (NN + BT - 1) / BT;
    const int edgeBlocks  = (NE + BT - 1) / BT;
    const int chunkBlocks = (NCHUNK + BT - 1) / BT;
    const int ndBlocks    = (NN * DH + BT - 1) / BT;
    const int nodeWaveBlocks = (NN * 64 + BT - 1) / BT;

    k_zero_init<<<nodeBlocks, BT, 0, stream>>>(deg);
    k_deg<<<edgeBlocks, BT, 0, stream>>>(ei, deg);
    k_scan_a<<<chunkBlocks, BT, 0, stream>>>(deg, part);
    k_scan_b<<<1, 64, 0, stream>>>(part);
    k_scan_c<<<chunkBlocks, BT, 0, stream>>>(deg, part, row, cursor);
    k_fill_csr<<<edgeBlocks, BT, 0, stream>>>(ei, ea, cursor, csr);
    k_fill_self<<<nodeBlocks, BT, 0, stream>>>(deg, row, csr);
    k_encoder<<<ndBlocks, BT, 0, stream>>>(x, enc_W, enc_b, hA);

    float* hin = hA;
    float* hout = hB;

    for (int L = 0; L < 3; L++) {
        if (L < 2) {
            constexpr int H = 4;
            constexpr int C = H * DH;
            k_xw_v4<C><<<((NN / 4) * (C / 8) + BT - 1) / BT, BT, 0, stream>>>(hin, lin_W[L], xw);
            k_att_s<H><<<(NN * H + BT - 1) / BT, BT, 0, stream>>>(xw, att_src[L], att_dst[L], a_srcB, a_dstB);
            k_coef_s<H><<<1, 64, 0, stream>>>(edge_W[L], att_edge[L], coef);
            k_mden<H><<<nodeBlocks, BT, 0, stream>>>(row, csr, a_srcB, a_dstB, coef, exbuf, mdenD);
            k_agg<H><<<nodeWaveBlocks, BT, 0, stream>>>(row, csr, exbuf, mdenD, xw, bias[L], hin, hout);
        } else {
            constexpr int H = 1;
            constexpr int C = H * DH;
            k_xw_v4<C><<<((NN / 4) * (C / 8) + BT - 1) / BT, BT, 0, stream>>>(hin, lin_W[L], xw);
            k_att_s<H><<<(NN * H + BT - 1) / BT, BT, 0, stream>>>(xw, att_src[L], att_dst[L], a_srcB, a_dstB);
            k_coef_s<H><<<1, 64, 0, stream>>>(edge_W[L], att_edge[L], coef);
            k_mden<H><<<nodeBlocks, BT, 0, stream>>>(row, csr, a_srcB, a_dstB, coef, exbuf, mdenD);
            k_agg<H><<<nodeWaveBlocks, BT, 0, stream>>>(row, csr, exbuf, mdenD, xw, bias[L], hin, hout);
        }
        float* t = hin; hin = hout; hout = t;
    }
    k_head_s<<<nodeBlocks, BT, 0, stream>>>(hin, fc1_W, fc1_b, fc2_W, fc2_b, out);
}

// Round 10
// 957.219 us; speedup vs baseline: 2.9568x; 1.0127x over previous
//
#include <hip/hip_runtime.h>
#include <math.h>

#define NN 100000
#define NE 1000000
#define DH 64
constexpr int ETOT = NE + NN;
constexpr int CHUNK = 100;
constexpr int NCHUNK = (NN + CHUNK - 1) / CHUNK;   // 1000

typedef _Float16 half_t;

// AoS edge record: {int src; float e0; float e1; int pad} stored as int4

// ---------------- degree ----------------

__global__ void k_zero_init(int* __restrict__ deg) {
    int i = blockIdx.x * blockDim.x + threadIdx.x;
    if (i < NN) deg[i] = 0;
}

__global__ void k_deg(const int* __restrict__ ei, int* __restrict__ deg) {
    int e = blockIdx.x * blockDim.x + threadIdx.x;
    if (e < NE) atomicAdd(&deg[ei[NE + e]], 1);
}

// ---------------- chunked prefix scan (scalar) ----------------

__global__ void k_scan_a(const int* __restrict__ deg, int* __restrict__ part) {
    int c = blockIdx.x * blockDim.x + threadIdx.x;
    if (c >= NCHUNK) return;
    int lo = c * CHUNK;
    int hi = lo + CHUNK; if (hi > NN) hi = NN;
    int s = 0;
    for (int i = lo; i < hi; i++) s += deg[i];
    part[c] = s;
}

__global__ void k_scan_b(int* __restrict__ part) {
    if (threadIdx.x || blockIdx.x) return;
    int run = 0;
    for (int i = 0; i < NCHUNK; i++) { int t = part[i]; part[i] = run; run += t; }
}

__global__ void k_scan_c(const int* __restrict__ deg, const int* __restrict__ part,
                         int* __restrict__ row, int* __restrict__ cursor) {
    int c = blockIdx.x * blockDim.x + threadIdx.x;
    if (c >= NCHUNK) return;
    int lo = c * CHUNK;
    int hi = lo + CHUNK; if (hi > NN) hi = NN;
    int run = part[c];
    for (int i = lo; i < hi; i++) {
        int r = run + i;
        row[i] = r;
        cursor[i] = r;
        run += deg[i];
    }
    if (c == NCHUNK - 1) row[NN] = run + NN;
}

__global__ void k_fill_csr(const int* __restrict__ ei, const float* __restrict__ ea,
                           int* __restrict__ cursor, int4* __restrict__ csr) {
    int e = blockIdx.x * blockDim.x + threadIdx.x;
    if (e < NE) {
        int s = ei[e];
        int d = ei[NE + e];
        int pos = atomicAdd(&cursor[d], 1);
        int4 rec;
        rec.x = s;
        rec.y = __float_as_int(ea[2 * e]);
        rec.z = __float_as_int(ea[2 * e + 1]);
        rec.w = 0;
        csr[pos] = rec;
    }
}

__global__ void k_fill_self(const int* __restrict__ deg, const int* __restrict__ row,
                            int4* __restrict__ csr) {
    int n = blockIdx.x * blockDim.x + threadIdx.x;
    if (n >= NN) return;
    int r0 = row[n];
    int dg = deg[n];
    float s0 = 0.f, s1 = 0.f;
    for (int j = r0; j < r0 + dg; j++) {
        int4 rec = csr[j];
        s0 += __int_as_float(rec.y);
        s1 += __int_as_float(rec.z);
    }
    float dv = fmaxf((float)dg, 1.0f);
    int4 self;
    self.x = n;
    self.y = __float_as_int(s0 / dv);
    self.z = __float_as_int(s1 / dv);
    self.w = 0;
    csr[r0 + dg] = self;
}

// ---------------- encoder: h = relu(x @ enc_W + enc_b), writes f32 + fp16 ----------------

__global__ void k_encoder(const float* __restrict__ x, const float* __restrict__ W,
                          const float* __restrict__ b, float* __restrict__ h,
                          half_t* __restrict__ h16) {
    int idx = blockIdx.x * blockDim.x + threadIdx.x;
    int n = idx >> 6, d = idx & 63;
    if (n < NN) {
        float v = x[2 * n] * W[d] + x[2 * n + 1] * W[DH + d] + b[d];
        v = fmaxf(v, 0.f);
        h[idx] = v;
        h16[idx] = (half_t)v;
    }
}

// ---------------- wsrc/wdst = lin_W @ att_{src,dst} per head (64 x H each) ----------------

template <int H>
__global__ void k_wsd(const float* __restrict__ lin_W, const float* __restrict__ att_src,
                      const float* __restrict__ att_dst,
                      float* __restrict__ wsrc, float* __restrict__ wdst) {
    constexpr int C = H * DH;
    int k = threadIdx.x;
    if (blockIdx.x || k >= DH) return;
#pragma unroll
    for (int h = 0; h < H; h++) {
        float ss = 0.f, sd = 0.f;
        for (int d = 0; d < DH; d++) {
            float w = lin_W[(size_t)k * C + h * DH + d];
            ss += w * att_src[h * DH + d];
            sd += w * att_dst[h * DH + d];
        }
        wsrc[k * H + h] = ss;
        wdst[k * H + h] = sd;
    }
}

// ---------------- a_src/a_dst directly from h: one thread per node ----------------

template <int H>
__global__ void k_att_h(const float* __restrict__ h, const float* __restrict__ wsrc,
                        const float* __restrict__ wdst,
                        float* __restrict__ a_src, float* __restrict__ a_dst) {
    int n = blockIdx.x * blockDim.x + threadIdx.x;
    if (n >= NN) return;
    float as[H], ad[H];
#pragma unroll
    for (int hh = 0; hh < H; hh++) { as[hh] = 0.f; ad[hh] = 0.f; }
    const float* hr = h + (size_t)n * DH;
    for (int k = 0; k < DH; k++) {
        float hv = hr[k];
#pragma unroll
        for (int hh = 0; hh < H; hh++) {
            as[hh] += hv * wsrc[k * H + hh];
            ad[hh] += hv * wdst[k * H + hh];
        }
    }
#pragma unroll
    for (int hh = 0; hh < H; hh++) {
        a_src[n * H + hh] = as[hh];
        a_dst[n * H + hh] = ad[hh];
    }
}

// ---------------- edge coef ----------------

template <int H>
__global__ void k_coef_s(const float* __restrict__ edge_W, const float* __restrict__ att_edge,
                         float* __restrict__ coef) {
    if (blockIdx.x || threadIdx.x) return;
    for (int w = 0; w < 2; w++)
        for (int h = 0; h < H; h++) {
            float s = 0.f;
            for (int d = 0; d < DH; d++)
                s += edge_W[w * H * DH + h * DH + d] * att_edge[h * DH + d];
            coef[w * H + h] = s;
        }
}

// ---------------- per-node den + normalized alpha (fp16): one THREAD per node ----------------
// exp(lg)/sum(exp(lg)) == max-subtracted form; logits O(+-10), f32-safe (validated R9).

template <int H>
__global__ void k_mden(const int* __restrict__ row, const int4* __restrict__ csr,
                       const float* __restrict__ a_src, const float* __restrict__ a_dst,
                       const float* __restrict__ coef, half_t* __restrict__ abuf) {
    int n = blockIdx.x * blockDim.x + threadIdx.x;
    if (n >= NN) return;
    int r0 = row[n], r1 = row[n + 1];
    float ad[H], cf[2 * H], den[H];
#pragma unroll
    for (int h = 0; h < H; h++) { ad[h] = a_dst[n * H + h]; den[h] = 0.f; }
#pragma unroll
    for (int i = 0; i < 2 * H; i++) cf[i] = coef[i];
    for (int j = r0; j < r1; j++) {
        int4 rec = csr[j];
        int s = rec.x;
        float e0 = __int_as_float(rec.y), e1 = __int_as_float(rec.z);
#pragma unroll
        for (int h = 0; h < H; h++) {
            float lg = a_src[s * H + h] + ad[h] + e0 * cf[h] + e1 * cf[H + h];
            lg = (lg > 0.f) ? lg : 0.2f * lg;
            den[h] += __expf(lg);
        }
    }
    float inv[H];
#pragma unroll
    for (int h = 0; h < H; h++) inv[h] = 1.f / (den[h] + 1e-16f);
    for (int j = r0; j < r1; j++) {
        int4 rec = csr[j];
        int s = rec.x;
        float e0 = __int_as_float(rec.y), e1 = __int_as_float(rec.z);
        half_t a4[H];
#pragma unroll
        for (int h = 0; h < H; h++) {
            float lg = a_src[s * H + h] + ad[h] + e0 * cf[h] + e1 * cf[H + h];
            lg = (lg > 0.f) ? lg : 0.2f * lg;
            a4[h] = (half_t)(__expf(lg) * inv[h]);
        }
        if constexpr (H == 4) {
            *(float2*)(abuf + (size_t)j * 4) = *(float2*)a4;
        } else {
            abuf[j] = a4[0];
        }
    }
}

// ---------------- aggregate on h (64-dim): one WAVE per node, lane = k ----------------

template <int H>
__global__ void k_agg_h(const int* __restrict__ row, const int4* __restrict__ csr,
                        const half_t* __restrict__ abuf, const half_t* __restrict__ h16,
                        half_t* __restrict__ agg) {
    int gid = blockIdx.x * blockDim.x + threadIdx.x;
    int n = gid >> 6;
    int lane = gid & 63;
    if (n >= NN) return;
    int r0 = row[n], r1 = row[n + 1];
    float acc[H];
#pragma unroll
    for (int h = 0; h < H; h++) acc[h] = 0.f;
    for (int j = r0; j < r1; j++) {
        int s = csr[j].x;                            // wave-uniform
        float av[H];
        if constexpr (H == 4) {
            float2 raw = *(const float2*)(abuf + (size_t)j * 4);   // uniform 8B
            const half_t* ap = (const half_t*)&raw;
#pragma unroll
            for (int h = 0; h < H; h++) av[h] = (float)ap[h];
        } else {
            av[0] = (float)abuf[j];
        }
        float hv = (float)h16[(size_t)s * DH + lane];  // 128B coalesced gather
#pragma unroll
        for (int h = 0; h < H; h++) acc[h] += av[h] * hv;
    }
#pragma unroll
    for (int h = 0; h < H; h++)
        agg[(size_t)n * (H * DH) + h * DH + lane] = (half_t)acc[h];
}

// ---------------- out = mean_h(agg_h @ W_h) + bias, relu, +res; 4 nodes x 8 cols ----------------

template <int H>
__global__ void k_out(const half_t* __restrict__ agg, const float* __restrict__ lin_W,
                      const float* __restrict__ bias, const float* __restrict__ hin,
                      float* __restrict__ hout, half_t* __restrict__ h16out) {
    constexpr int C = H * DH;
    constexpr int TPN = DH / 8;                // 8 threads per 4-node group
    int gid = blockIdx.x * blockDim.x + threadIdx.x;
    int nb = gid / TPN;
    int c0 = (gid % TPN) * 8;
    if (nb >= NN / 4) return;
    int n0 = nb * 4;
    float acc[4][8];
#pragma unroll
    for (int i = 0; i < 4; i++)
#pragma unroll
        for (int j = 0; j < 8; j++) acc[i][j] = 0.f;
#pragma unroll
    for (int h = 0; h < H; h++) {
        for (int q = 0; q < DH / 4; q++) {
            float areg[4][4];
#pragma unroll
            for (int i = 0; i < 4; i++) {
                float2 raw = *(const float2*)(agg + (size_t)(n0 + i) * C + h * DH + q * 4);
                const half_t* ap = (const half_t*)&raw;
                areg[i][0] = (float)ap[0]; areg[i][1] = (float)ap[1];
                areg[i][2] = (float)ap[2]; areg[i][3] = (float)ap[3];
            }
#pragma unroll
            for (int t = 0; t < 4; t++) {
                int k = q * 4 + t;
                const float4* w4 = (const float4*)(lin_W + (size_t)k * C + h * DH + c0);
                float4 a = w4[0], b = w4[1];
                float wv[8] = {a.x, a.y, a.z, a.w, b.x, b.y, b.z, b.w};
#pragma unroll
                for (int i = 0; i < 4; i++) {
                    float av = areg[i][t];
#pragma unroll
                    for (int j = 0; j < 8; j++) acc[i][j] += av * wv[j];
                }
            }
        }
    }
    float bv[8];
#pragma unroll
    for (int j = 0; j < 8; j++) bv[j] = bias[c0 + j];
#pragma unroll
    for (int i = 0; i < 4; i++) {
        const float* rp = hin + (size_t)(n0 + i) * DH + c0;
        float ov[8];
        half_t hv[8];
#pragma unroll
        for (int j = 0; j < 8; j++) {
            float v = acc[i][j] * (1.0f / H) + bv[j];
            v = fmaxf(v, 0.f) + rp[j];
            ov[j] = v;
            hv[j] = (half_t)v;
        }
        float* op = hout + (size_t)(n0 + i) * DH + c0;
        *(float4*)(op)     = make_float4(ov[0], ov[1], ov[2], ov[3]);
        *(float4*)(op + 4) = make_float4(ov[4], ov[5], ov[6], ov[7]);
        *(float4*)(h16out + (size_t)(n0 + i) * DH + c0) = *(float4*)hv;
    }
}

// ---------------- final MLP head ----------------

__global__ void k_head_s(const float* __restrict__ h, const float* __restrict__ fc1_W,
                         const float* __restrict__ fc1_b, const float* __restrict__ fc2_W,
                         const float* __restrict__ fc2_b, float* __restrict__ out) {
    int n = blockIdx.x * blockDim.x + threadIdx.x;
    if (n >= NN) return;
    float y[32];
#pragma unroll
    for (int c = 0; c < 32; c++) y[c] = fc1_b[c];
    for (int k = 0; k < DH; k++) {
        float hk = h[n * DH + k];
#pragma unroll
        for (int c = 0; c < 32; c++) y[c] += hk * fc1_W[k * 32 + c];
    }
    float o0 = fc2_b[0], o1 = fc2_b[1];
#pragma unroll
    for (int c = 0; c < 32; c++) {
        float yr = fmaxf(y[c], 0.f);
        o0 += yr * fc2_W[c * 2];
        o1 += yr * fc2_W[c * 2 + 1];
    }
    out[2 * n] = tanhf(o0);
    out[2 * n + 1] = tanhf(o1);
}

// ---------------- launch ----------------

extern "C" void kernel_launch(void* const* d_in, const int* in_sizes, int n_in,
                              void* d_out, int out_size, void* d_ws, size_t ws_size,
                              hipStream_t stream) {
    const float* x     = (const float*)d_in[0];
    const int*   ei    = (const int*)d_in[1];
    const float* ea    = (const float*)d_in[2];
    const float* enc_W = (const float*)d_in[3];
    const float* enc_b = (const float*)d_in[4];
    const float* lin_W[3]    = {(const float*)d_in[5],  (const float*)d_in[11], (const float*)d_in[17]};
    const float* att_src[3]  = {(const float*)d_in[6],  (const float*)d_in[12], (const float*)d_in[18]};
    const float* att_dst[3]  = {(const float*)d_in[7],  (const float*)d_in[13], (const float*)d_in[19]};
    const float* edge_W[3]   = {(const float*)d_in[8],  (const float*)d_in[14], (const float*)d_in[20]};
    const float* att_edge[3] = {(const float*)d_in[9],  (const float*)d_in[15], (const float*)d_in[21]};
    const float* bias[3]     = {(const float*)d_in[10], (const float*)d_in[16], (const float*)d_in[22]};
    const float* fc1_W = (const float*)d_in[23];
    const float* fc1_b = (const float*)d_in[24];
    const float* fc2_W = (const float*)d_in[25];
    const float* fc2_b = (const float*)d_in[26];
    float* out = (float*)d_out;

    char* p = (char*)d_ws;
    auto alloc = [&](size_t bytes) -> void* {
        void* r = (void*)p;
        p += (bytes + 255) & ~(size_t)255;
        return r;
    };
    int*    deg    = (int*)alloc((size_t)NN * 4);
    int*    part   = (int*)alloc((size_t)NCHUNK * 4);
    int*    row    = (int*)alloc((size_t)(NN + 1) * 4);
    int*    cursor = (int*)alloc((size_t)NN * 4);
    int4*   csr    = (int4*)alloc((size_t)ETOT * 16);
    float*  a_srcB = (float*)alloc((size_t)NN * 4 * 4);
    float*  a_dstB = (float*)alloc((size_t)NN * 4 * 4);
    float*  coef   = (float*)alloc(256);
    float*  wsrc   = (float*)alloc((size_t)DH * 4 * 4);
    float*  wdst   = (float*)alloc((size_t)DH * 4 * 4);
    half_t* abuf   = (half_t*)alloc((size_t)ETOT * 4 * 2);
    half_t* aggB   = (half_t*)alloc((size_t)NN * 256 * 2);
    half_t* h16    = (half_t*)alloc((size_t)NN * DH * 2);
    float*  hA     = (float*)alloc((size_t)NN * DH * 4);
    float*  hB     = (float*)alloc((size_t)NN * DH * 4);

    const int BT = 256;
    const int nodeBlocks  = (NN + BT - 1) / BT;
    const int edgeBlocks  = (NE + BT - 1) / BT;
    const int chunkBlocks = (NCHUNK + BT - 1) / BT;
    const int ndBlocks    = (NN * DH + BT - 1) / BT;
    const int nodeWaveBlocks = (NN * 64 + BT - 1) / BT;
    const int outBlocks   = ((NN / 4) * (DH / 8) + BT - 1) / BT;

    k_zero_init<<<nodeBlocks, BT, 0, stream>>>(deg);
    k_deg<<<edgeBlocks, BT, 0, stream>>>(ei, deg);
    k_scan_a<<<chunkBlocks, BT, 0, stream>>>(deg, part);
    k_scan_b<<<1, 64, 0, stream>>>(part);
    k_scan_c<<<chunkBlocks, BT, 0, stream>>>(deg, part, row, cursor);
    k_fill_csr<<<edgeBlocks, BT, 0, stream>>>(ei, ea, cursor, csr);
    k_fill_self<<<nodeBlocks, BT, 0, stream>>>(deg, row, csr);
    k_encoder<<<ndBlocks, BT, 0, stream>>>(x, enc_W, enc_b, hA, h16);

    float* hin = hA;
    float* hout = hB;

    for (int L = 0; L < 3; L++) {
        if (L < 2) {
            constexpr int H = 4;
            k_wsd<H><<<1, 64, 0, stream>>>(lin_W[L], att_src[L], att_dst[L], wsrc, wdst);
            k_att_h<H><<<nodeBlocks, BT, 0, stream>>>(hin, wsrc, wdst, a_srcB, a_dstB);
            k_coef_s<H><<<1, 64, 0, stream>>>(edge_W[L], att_edge[L], coef);
            k_mden<H><<<nodeBlocks, BT, 0, stream>>>(row, csr, a_srcB, a_dstB, coef, abuf);
            k_agg_h<H><<<nodeWaveBlocks, BT, 0, stream>>>(row, csr, abuf, h16, aggB);
            k_out<H><<<outBlocks, BT, 0, stream>>>(aggB, lin_W[L], bias[L], hin, hout, h16);
        } else {
            constexpr int H = 1;
            k_wsd<H><<<1, 64, 0, stream>>>(lin_W[L], att_src[L], att_dst[L], wsrc, wdst);
            k_att_h<H><<<nodeBlocks, BT, 0, stream>>>(hin, wsrc, wdst, a_srcB, a_dstB);
            k_coef_s<H><<<1, 64, 0, stream>>>(edge_W[L], att_edge[L], coef);
            k_mden<H><<<nodeBlocks, BT, 0, stream>>>(row, csr, a_srcB, a_dstB, coef, abuf);
            k_agg_h<H><<<nodeWaveBlocks, BT, 0, stream>>>(row, csr, abuf, h16, aggB);
            k_out<H><<<outBlocks, BT, 0, stream>>>(aggB, lin_W[L], bias[L], hin, hout, h16);
        }
        float* t = hin; hin = hout; hout = t;
    }
    k_head_s<<<nodeBlocks, BT, 0, stream>>>(hin, fc1_W, fc1_b, fc2_W, fc2_b, out);
}

// Round 11
// 777.825 us; speedup vs baseline: 3.6387x; 1.2306x over previous
//
#include <hip/hip_runtime.h>
#include <math.h>

#define NN 100000
#define NE 1000000
#define DH 64
constexpr int ETOT = NE + NN;
constexpr int CHUNK = 100;
constexpr int NCHUNK = (NN + CHUNK - 1) / CHUNK;   // 1000

typedef _Float16 half_t;

// AoS edge record: {int src; float e0; float e1; int pad} stored as int4

// ---------------- degree ----------------

__global__ void k_zero_init(int* __restrict__ deg) {
    int i = blockIdx.x * blockDim.x + threadIdx.x;
    if (i < NN) deg[i] = 0;
}

__global__ void k_deg(const int* __restrict__ ei, int* __restrict__ deg) {
    int e = blockIdx.x * blockDim.x + threadIdx.x;
    if (e < NE) atomicAdd(&deg[ei[NE + e]], 1);
}

// ---------------- chunked prefix scan (scalar) ----------------

__global__ void k_scan_a(const int* __restrict__ deg, int* __restrict__ part) {
    int c = blockIdx.x * blockDim.x + threadIdx.x;
    if (c >= NCHUNK) return;
    int lo = c * CHUNK;
    int hi = lo + CHUNK; if (hi > NN) hi = NN;
    int s = 0;
    for (int i = lo; i < hi; i++) s += deg[i];
    part[c] = s;
}

__global__ void k_scan_b(int* __restrict__ part) {
    if (threadIdx.x || blockIdx.x) return;
    int run = 0;
    for (int i = 0; i < NCHUNK; i++) { int t = part[i]; part[i] = run; run += t; }
}

__global__ void k_scan_c(const int* __restrict__ deg, const int* __restrict__ part,
                         int* __restrict__ row, int* __restrict__ cursor) {
    int c = blockIdx.x * blockDim.x + threadIdx.x;
    if (c >= NCHUNK) return;
    int lo = c * CHUNK;
    int hi = lo + CHUNK; if (hi > NN) hi = NN;
    int run = part[c];
    for (int i = lo; i < hi; i++) {
        int r = run + i;
        row[i] = r;
        cursor[i] = r;
        run += deg[i];
    }
    if (c == NCHUNK - 1) row[NN] = run + NN;
}

__global__ void k_fill_csr(const int* __restrict__ ei, const float* __restrict__ ea,
                           int* __restrict__ cursor, int4* __restrict__ csr) {
    int e = blockIdx.x * blockDim.x + threadIdx.x;
    if (e < NE) {
        int s = ei[e];
        int d = ei[NE + e];
        int pos = atomicAdd(&cursor[d], 1);
        int4 rec;
        rec.x = s;
        rec.y = __float_as_int(ea[2 * e]);
        rec.z = __float_as_int(ea[2 * e + 1]);
        rec.w = 0;
        csr[pos] = rec;
    }
}

__global__ void k_fill_self(const int* __restrict__ deg, const int* __restrict__ row,
                            int4* __restrict__ csr) {
    int n = blockIdx.x * blockDim.x + threadIdx.x;
    if (n >= NN) return;
    int r0 = row[n];
    int dg = deg[n];
    float s0 = 0.f, s1 = 0.f;
    for (int j = r0; j < r0 + dg; j++) {
        int4 rec = csr[j];
        s0 += __int_as_float(rec.y);
        s1 += __int_as_float(rec.z);
    }
    float dv = fmaxf((float)dg, 1.0f);
    int4 self;
    self.x = n;
    self.y = __float_as_int(s0 / dv);
    self.z = __float_as_int(s1 / dv);
    self.w = 0;
    csr[r0 + dg] = self;
}

// ---------------- encoder: h = relu(x @ enc_W + enc_b), writes f32 + fp16 ----------------

__global__ void k_encoder(const float* __restrict__ x, const float* __restrict__ W,
                          const float* __restrict__ b, float* __restrict__ h,
                          half_t* __restrict__ h16) {
    int idx = blockIdx.x * blockDim.x + threadIdx.x;
    int n = idx >> 6, d = idx & 63;
    if (n < NN) {
        float v = x[2 * n] * W[d] + x[2 * n + 1] * W[DH + d] + b[d];
        v = fmaxf(v, 0.f);
        h[idx] = v;
        h16[idx] = (half_t)v;
    }
}

// ---------------- fused prep (all 3 layers): wsrc/wdst = lin_W@att_*, coef = edge_W@att_edge ----
// wsrc/wdst layout: L0 at [0,256), L1 at [256,512), L2 at [512,576) (stride H per k)
// coef layout: L0 at [0,8), L1 at [8,16), L2 at [16,18)

__global__ void k_prep(const float* __restrict__ lw0, const float* __restrict__ as0,
                       const float* __restrict__ ad0, const float* __restrict__ ew0,
                       const float* __restrict__ ae0,
                       const float* __restrict__ lw1, const float* __restrict__ as1,
                       const float* __restrict__ ad1, const float* __restrict__ ew1,
                       const float* __restrict__ ae1,
                       const float* __restrict__ lw2, const float* __restrict__ as2,
                       const float* __restrict__ ad2, const float* __restrict__ ew2,
                       const float* __restrict__ ae2,
                       float* __restrict__ wsrc, float* __restrict__ wdst,
                       float* __restrict__ coef) {
    int L = blockIdx.x;
    int k = threadIdx.x;
    if (k >= DH) return;
    const float* lw = (L == 0) ? lw0 : (L == 1) ? lw1 : lw2;
    const float* as = (L == 0) ? as0 : (L == 1) ? as1 : as2;
    const float* ad = (L == 0) ? ad0 : (L == 1) ? ad1 : ad2;
    const float* ew = (L == 0) ? ew0 : (L == 1) ? ew1 : ew2;
    const float* ae = (L == 0) ? ae0 : (L == 1) ? ae1 : ae2;
    int H = (L < 2) ? 4 : 1;
    int C = H * DH;
    int wo = (L == 0) ? 0 : (L == 1) ? 256 : 512;
    for (int h = 0; h < H; h++) {
        float ss = 0.f, sd = 0.f;
        for (int d = 0; d < DH; d++) {
            float w = lw[(size_t)k * C + h * DH + d];
            ss += w * as[h * DH + d];
            sd += w * ad[h * DH + d];
        }
        wsrc[wo + k * H + h] = ss;
        wdst[wo + k * H + h] = sd;
    }
    if (k == 0) {
        int co = (L == 0) ? 0 : (L == 1) ? 8 : 16;
        for (int w = 0; w < 2; w++)
            for (int h = 0; h < H; h++) {
                float s = 0.f;
                for (int d = 0; d < DH; d++)
                    s += ew[w * H * DH + h * DH + d] * ae[h * DH + d];
                coef[co + w * H + h] = s;
            }
    }
}

// ---------------- a_src/a_dst directly from h: one thread per node ----------------

template <int H>
__global__ void k_att_h(const float* __restrict__ h, const float* __restrict__ wsrc,
                        const float* __restrict__ wdst,
                        float* __restrict__ a_src, float* __restrict__ a_dst) {
    int n = blockIdx.x * blockDim.x + threadIdx.x;
    if (n >= NN) return;
    float as[H], ad[H];
#pragma unroll
    for (int hh = 0; hh < H; hh++) { as[hh] = 0.f; ad[hh] = 0.f; }
    const float* hr = h + (size_t)n * DH;
    for (int k = 0; k < DH; k++) {
        float hv = hr[k];
#pragma unroll
        for (int hh = 0; hh < H; hh++) {
            as[hh] += hv * wsrc[k * H + hh];
            ad[hh] += hv * wdst[k * H + hh];
        }
    }
#pragma unroll
    for (int hh = 0; hh < H; hh++) {
        a_src[n * H + hh] = as[hh];
        a_dst[n * H + hh] = ad[hh];
    }
}

// ---------------- per-node den + normalized alpha (fp16): one THREAD per node ----------------

template <int H>
__global__ void k_mden(const int* __restrict__ row, const int4* __restrict__ csr,
                       const float* __restrict__ a_src, const float* __restrict__ a_dst,
                       const float* __restrict__ coef, half_t* __restrict__ abuf) {
    int n = blockIdx.x * blockDim.x + threadIdx.x;
    if (n >= NN) return;
    int r0 = row[n], r1 = row[n + 1];
    float ad[H], cf[2 * H], den[H];
#pragma unroll
    for (int h = 0; h < H; h++) { ad[h] = a_dst[n * H + h]; den[h] = 0.f; }
#pragma unroll
    for (int i = 0; i < 2 * H; i++) cf[i] = coef[i];
    for (int j = r0; j < r1; j++) {
        int4 rec = csr[j];
        int s = rec.x;
        float e0 = __int_as_float(rec.y), e1 = __int_as_float(rec.z);
#pragma unroll
        for (int h = 0; h < H; h++) {
            float lg = a_src[s * H + h] + ad[h] + e0 * cf[h] + e1 * cf[H + h];
            lg = (lg > 0.f) ? lg : 0.2f * lg;
            den[h] += __expf(lg);
        }
    }
    float inv[H];
#pragma unroll
    for (int h = 0; h < H; h++) inv[h] = 1.f / (den[h] + 1e-16f);
    for (int j = r0; j < r1; j++) {
        int4 rec = csr[j];
        int s = rec.x;
        float e0 = __int_as_float(rec.y), e1 = __int_as_float(rec.z);
        half_t a4[H];
#pragma unroll
        for (int h = 0; h < H; h++) {
            float lg = a_src[s * H + h] + ad[h] + e0 * cf[h] + e1 * cf[H + h];
            lg = (lg > 0.f) ? lg : 0.2f * lg;
            a4[h] = (half_t)(__expf(lg) * inv[h]);
        }
        if constexpr (H == 4) {
            *(float2*)(abuf + (size_t)j * 4) = *(float2*)a4;
        } else {
            abuf[j] = a4[0];
        }
    }
}

// ---------------- aggregate on h: one WAVE per node, lane = k, 4-edge pipelined ----------------

template <int H>
__global__ void k_agg_h(const int* __restrict__ row, const int4* __restrict__ csr,
                        const half_t* __restrict__ abuf, const half_t* __restrict__ h16,
                        half_t* __restrict__ agg) {
    int gid = blockIdx.x * blockDim.x + threadIdx.x;
    int n = gid >> 6;
    int lane = gid & 63;
    if (n >= NN) return;
    int r0 = row[n], r1 = row[n + 1];
    float acc[H];
#pragma unroll
    for (int h = 0; h < H; h++) acc[h] = 0.f;
    int j = r0;
    // 4-edge software pipeline: all loads issued before use, breaking the
    // per-edge dependent chain csr[j] -> h16 gather (latency-bound at R10).
    for (; j + 4 <= r1; j += 4) {
        int s0 = csr[j].x, s1 = csr[j + 1].x, s2 = csr[j + 2].x, s3 = csr[j + 3].x;
        float av[4][H];
        if constexpr (H == 4) {
            float2 r0v = *(const float2*)(abuf + (size_t)(j + 0) * 4);
            float2 r1v = *(const float2*)(abuf + (size_t)(j + 1) * 4);
            float2 r2v = *(const float2*)(abuf + (size_t)(j + 2) * 4);
            float2 r3v = *(const float2*)(abuf + (size_t)(j + 3) * 4);
            const half_t* p0 = (const half_t*)&r0v;
            const half_t* p1 = (const half_t*)&r1v;
            const half_t* p2 = (const half_t*)&r2v;
            const half_t* p3 = (const half_t*)&r3v;
#pragma unroll
            for (int h = 0; h < 4; h++) {
                av[0][h] = (float)p0[h]; av[1][h] = (float)p1[h];
                av[2][h] = (float)p2[h]; av[3][h] = (float)p3[h];
            }
        } else {
            av[0][0] = (float)abuf[j];     av[1][0] = (float)abuf[j + 1];
            av[2][0] = (float)abuf[j + 2]; av[3][0] = (float)abuf[j + 3];
        }
        float hv0 = (float)h16[(size_t)s0 * DH + lane];
        float hv1 = (float)h16[(size_t)s1 * DH + lane];
        float hv2 = (float)h16[(size_t)s2 * DH + lane];
        float hv3 = (float)h16[(size_t)s3 * DH + lane];
#pragma unroll
        for (int h = 0; h < H; h++) acc[h] += av[0][h] * hv0;
#pragma unroll
        for (int h = 0; h < H; h++) acc[h] += av[1][h] * hv1;
#pragma unroll
        for (int h = 0; h < H; h++) acc[h] += av[2][h] * hv2;
#pragma unroll
        for (int h = 0; h < H; h++) acc[h] += av[3][h] * hv3;
    }
    for (; j < r1; j++) {
        int s = csr[j].x;
        float av[H];
        if constexpr (H == 4) {
            float2 raw = *(const float2*)(abuf + (size_t)j * 4);
            const half_t* ap = (const half_t*)&raw;
#pragma unroll
            for (int h = 0; h < H; h++) av[h] = (float)ap[h];
        } else {
            av[0] = (float)abuf[j];
        }
        float hv = (float)h16[(size_t)s * DH + lane];
#pragma unroll
        for (int h = 0; h < H; h++) acc[h] += av[h] * hv;
    }
#pragma unroll
    for (int h = 0; h < H; h++)
        agg[(size_t)n * (H * DH) + h * DH + lane] = (half_t)acc[h];
}

// ---------------- out = mean_h(agg_h @ W_h) + bias, relu, +res; 4 nodes x 8 cols ----------------

template <int H>
__global__ void k_out(const half_t* __restrict__ agg, const float* __restrict__ lin_W,
                      const float* __restrict__ bias, const float* __restrict__ hin,
                      float* __restrict__ hout, half_t* __restrict__ h16out) {
    constexpr int C = H * DH;
    constexpr int TPN = DH / 8;
    int gid = blockIdx.x * blockDim.x + threadIdx.x;
    int nb = gid / TPN;
    int c0 = (gid % TPN) * 8;
    if (nb >= NN / 4) return;
    int n0 = nb * 4;
    float acc[4][8];
#pragma unroll
    for (int i = 0; i < 4; i++)
#pragma unroll
        for (int j = 0; j < 8; j++) acc[i][j] = 0.f;
#pragma unroll
    for (int h = 0; h < H; h++) {
        for (int q = 0; q < DH / 4; q++) {
            float areg[4][4];
#pragma unroll
            for (int i = 0; i < 4; i++) {
                float2 raw = *(const float2*)(agg + (size_t)(n0 + i) * C + h * DH + q * 4);
                const half_t* ap = (const half_t*)&raw;
                areg[i][0] = (float)ap[0]; areg[i][1] = (float)ap[1];
                areg[i][2] = (float)ap[2]; areg[i][3] = (float)ap[3];
            }
#pragma unroll
            for (int t = 0; t < 4; t++) {
                int k = q * 4 + t;
                const float4* w4 = (const float4*)(lin_W + (size_t)k * C + h * DH + c0);
                float4 a = w4[0], b = w4[1];
                float wv[8] = {a.x, a.y, a.z, a.w, b.x, b.y, b.z, b.w};
#pragma unroll
                for (int i = 0; i < 4; i++) {
                    float av = areg[i][t];
#pragma unroll
                    for (int j = 0; j < 8; j++) acc[i][j] += av * wv[j];
                }
            }
        }
    }
    float bv[8];
#pragma unroll
    for (int j = 0; j < 8; j++) bv[j] = bias[c0 + j];
#pragma unroll
    for (int i = 0; i < 4; i++) {
        const float* rp = hin + (size_t)(n0 + i) * DH + c0;
        float ov[8];
        half_t hv[8];
#pragma unroll
        for (int j = 0; j < 8; j++) {
            float v = acc[i][j] * (1.0f / H) + bv[j];
            v = fmaxf(v, 0.f) + rp[j];
            ov[j] = v;
            hv[j] = (half_t)v;
        }
        float* op = hout + (size_t)(n0 + i) * DH + c0;
        *(float4*)(op)     = make_float4(ov[0], ov[1], ov[2], ov[3]);
        *(float4*)(op + 4) = make_float4(ov[4], ov[5], ov[6], ov[7]);
        *(float4*)(h16out + (size_t)(n0 + i) * DH + c0) = *(float4*)hv;
    }
}

// ---------------- final MLP head ----------------

__global__ void k_head_s(const float* __restrict__ h, const float* __restrict__ fc1_W,
                         const float* __restrict__ fc1_b, const float* __restrict__ fc2_W,
                         const float* __restrict__ fc2_b, float* __restrict__ out) {
    int n = blockIdx.x * blockDim.x + threadIdx.x;
    if (n >= NN) return;
    float y[32];
#pragma unroll
    for (int c = 0; c < 32; c++) y[c] = fc1_b[c];
    for (int k = 0; k < DH; k++) {
        float hk = h[n * DH + k];
#pragma unroll
        for (int c = 0; c < 32; c++) y[c] += hk * fc1_W[k * 32 + c];
    }
    float o0 = fc2_b[0], o1 = fc2_b[1];
#pragma unroll
    for (int c = 0; c < 32; c++) {
        float yr = fmaxf(y[c], 0.f);
        o0 += yr * fc2_W[c * 2];
        o1 += yr * fc2_W[c * 2 + 1];
    }
    out[2 * n] = tanhf(o0);
    out[2 * n + 1] = tanhf(o1);
}

// ---------------- launch ----------------

extern "C" void kernel_launch(void* const* d_in, const int* in_sizes, int n_in,
                              void* d_out, int out_size, void* d_ws, size_t ws_size,
                              hipStream_t stream) {
    const float* x     = (const float*)d_in[0];
    const int*   ei    = (const int*)d_in[1];
    const float* ea    = (const float*)d_in[2];
    const float* enc_W = (const float*)d_in[3];
    const float* enc_b = (const float*)d_in[4];
    const float* lin_W[3]    = {(const float*)d_in[5],  (const float*)d_in[11], (const float*)d_in[17]};
    const float* att_src[3]  = {(const float*)d_in[6],  (const float*)d_in[12], (const float*)d_in[18]};
    const float* att_dst[3]  = {(const float*)d_in[7],  (const float*)d_in[13], (const float*)d_in[19]};
    const float* edge_W[3]   = {(const float*)d_in[8],  (const float*)d_in[14], (const float*)d_in[20]};
    const float* att_edge[3] = {(const float*)d_in[9],  (const float*)d_in[15], (const float*)d_in[21]};
    const float* bias[3]     = {(const float*)d_in[10], (const float*)d_in[16], (const float*)d_in[22]};
    const float* fc1_W = (const float*)d_in[23];
    const float* fc1_b = (const float*)d_in[24];
    const float* fc2_W = (const float*)d_in[25];
    const float* fc2_b = (const float*)d_in[26];
    float* out = (float*)d_out;

    char* p = (char*)d_ws;
    auto alloc = [&](size_t bytes) -> void* {
        void* r = (void*)p;
        p += (bytes + 255) & ~(size_t)255;
        return r;
    };
    int*    deg    = (int*)alloc((size_t)NN * 4);
    int*    part   = (int*)alloc((size_t)NCHUNK * 4);
    int*    row    = (int*)alloc((size_t)(NN + 1) * 4);
    int*    cursor = (int*)alloc((size_t)NN * 4);
    int4*   csr    = (int4*)alloc((size_t)ETOT * 16);
    float*  a_srcB = (float*)alloc((size_t)NN * 4 * 4);
    float*  a_dstB = (float*)alloc((size_t)NN * 4 * 4);
    float*  wsrcA  = (float*)alloc(576 * 4);
    float*  wdstA  = (float*)alloc(576 * 4);
    float*  coefA  = (float*)alloc(18 * 4);
    half_t* abuf   = (half_t*)alloc((size_t)ETOT * 4 * 2);
    half_t* aggB   = (half_t*)alloc((size_t)NN * 256 * 2);
    half_t* h16    = (half_t*)alloc((size_t)NN * DH * 2);
    float*  hA     = (float*)alloc((size_t)NN * DH * 4);
    float*  hB     = (float*)alloc((size_t)NN * DH * 4);

    const int BT = 256;
    const int nodeBlocks  = (NN + BT - 1) / BT;
    const int edgeBlocks  = (NE + BT - 1) / BT;
    const int chunkBlocks = (NCHUNK + BT - 1) / BT;
    const int ndBlocks    = (NN * DH + BT - 1) / BT;
    const int nodeWaveBlocks = (NN * 64 + BT - 1) / BT;
    const int outBlocks   = ((NN / 4) * (DH / 8) + BT - 1) / BT;

    k_zero_init<<<nodeBlocks, BT, 0, stream>>>(deg);
    k_deg<<<edgeBlocks, BT, 0, stream>>>(ei, deg);
    k_scan_a<<<chunkBlocks, BT, 0, stream>>>(deg, part);
    k_scan_b<<<1, 64, 0, stream>>>(part);
    k_scan_c<<<chunkBlocks, BT, 0, stream>>>(deg, part, row, cursor);
    k_fill_csr<<<edgeBlocks, BT, 0, stream>>>(ei, ea, cursor, csr);
    k_fill_self<<<nodeBlocks, BT, 0, stream>>>(deg, row, csr);
    k_encoder<<<ndBlocks, BT, 0, stream>>>(x, enc_W, enc_b, hA, h16);
    k_prep<<<3, 64, 0, stream>>>(lin_W[0], att_src[0], att_dst[0], edge_W[0], att_edge[0],
                                 lin_W[1], att_src[1], att_dst[1], edge_W[1], att_edge[1],
                                 lin_W[2], att_src[2], att_dst[2], edge_W[2], att_edge[2],
                                 wsrcA, wdstA, coefA);

    float* hin = hA;
    float* hout = hB;

    for (int L = 0; L < 3; L++) {
        const float* ws = wsrcA + ((L == 0) ? 0 : (L == 1) ? 256 : 512);
        const float* wd = wdstA + ((L == 0) ? 0 : (L == 1) ? 256 : 512);
        const float* cf = coefA + ((L == 0) ? 0 : (L == 1) ? 8 : 16);
        if (L < 2) {
            constexpr int H = 4;
            k_att_h<H><<<nodeBlocks, BT, 0, stream>>>(hin, ws, wd, a_srcB, a_dstB);
            k_mden<H><<<nodeBlocks, BT, 0, stream>>>(row, csr, a_srcB, a_dstB, cf, abuf);
            k_agg_h<H><<<nodeWaveBlocks, BT, 0, stream>>>(row, csr, abuf, h16, aggB);
            k_out<H><<<outBlocks, BT, 0, stream>>>(aggB, lin_W[L], bias[L], hin, hout, h16);
        } else {
            constexpr int H = 1;
            k_att_h<H><<<nodeBlocks, BT, 0, stream>>>(hin, ws, wd, a_srcB, a_dstB);
            k_mden<H><<<nodeBlocks, BT, 0, stream>>>(row, csr, a_srcB, a_dstB, cf, abuf);
            k_agg_h<H><<<nodeWaveBlocks, BT, 0, stream>>>(row, csr, abuf, h16, aggB);
            k_out<H><<<outBlocks, BT, 0, stream>>>(aggB, lin_W[L], bias[L], hin, hout, h16);
        }
        float* t = hin; hin = hout; hout = t;
    }
    k_head_s<<<nodeBlocks, BT, 0, stream>>>(hin, fc1_W, fc1_b, fc2_W, fc2_b, out);
}